// Round 1
// baseline (890.312 us; speedup 1.0000x reference)
//
#include <hip/hip_runtime.h>
#include <hip/hip_bf16.h>

typedef __attribute__((ext_vector_type(8))) short short8;
typedef __attribute__((ext_vector_type(4))) short short4v;
typedef __attribute__((ext_vector_type(4))) float floatx4;

__device__ __forceinline__ float b2f(ushort u) {
  unsigned x = ((unsigned)u) << 16;
  return __builtin_bit_cast(float, x);
}
__device__ __forceinline__ ushort f2b(float f) {
  unsigned x = __builtin_bit_cast(unsigned, f);
  x += 0x7fffu + ((x >> 16) & 1u);
  return (ushort)(x >> 16);
}

__device__ __forceinline__ void gload_lds16(const void* g, void* l) {
  __builtin_amdgcn_global_load_lds(
      (const __attribute__((address_space(1))) unsigned int*)g,
      (__attribute__((address_space(3))) unsigned int*)l, 16, 0, 0);
}

// ---------------- f32 -> bf16 conversion ----------------
__global__ __launch_bounds__(256) void cvt_kernel(const float* __restrict__ in,
                                                  ushort* __restrict__ out, long n) {
  long i0 = ((long)blockIdx.x * 256 + threadIdx.x) * 4;
  long stride = (long)gridDim.x * 256 * 4;
  for (long i = i0; i < n; i += stride) {
    float4 v = *(const float4*)(in + i);
    ushort4 u;
    u.x = f2b(v.x); u.y = f2b(v.y); u.z = f2b(v.z); u.w = f2b(v.w);
    *(ushort4*)(out + i) = u;
  }
}

// ---------------- GEMM: C[M,N] = A[M,K] * B[N,K]^T (bf16 in, f32 acc) ----------------
// m97 structure: 128x128 tile, BK=32, 4 waves (2x2 of 64x64), global_load_lds w=16,
// chunk-XOR swizzle (4-way instead of 8-way ds_read_b128 conflicts).
template <int OUTBF16>
__global__ __launch_bounds__(256, 2)
void gemm_bt(const ushort* __restrict__ A, const ushort* __restrict__ B,
             float* __restrict__ Cf, ushort* __restrict__ Cb,
             int M, int N, int K) {
  __shared__ __align__(16) ushort Alds[128 * 32];
  __shared__ __align__(16) ushort Blds[128 * 32];
  const int t = threadIdx.x;
  const int lane = t & 63;
  const int w = t >> 6;
  const int ntn = N >> 7;
  const int nwg = gridDim.x;
  const int wg = blockIdx.x;
  const int swz = (wg & 7) * (nwg >> 3) + (wg >> 3);  // bijective: nwg % 8 == 0
  const int m0 = (swz / ntn) << 7;
  const int n0 = (swz % ntn) << 7;
  const int wr = w >> 1, wc = w & 1;

  floatx4 acc[4][4];
#pragma unroll
  for (int i = 0; i < 4; i++)
#pragma unroll
    for (int j = 0; j < 4; j++) acc[i][j] = (floatx4)(0.0f);

  const ushort* Ab = A + (size_t)m0 * K;
  const ushort* Bb = B + (size_t)n0 * K;

  for (int k0 = 0; k0 < K; k0 += 32) {
#pragma unroll
    for (int j = 0; j < 2; ++j) {
      const int c = j * 256 + t;              // 512 16B chunks per tile
      const int row = c >> 2;
      const int cols = ((c & 3) ^ (row & 3)) * 8;  // source-side swizzle
      gload_lds16(Ab + (size_t)row * K + k0 + cols, (char*)Alds + c * 16);
      gload_lds16(Bb + (size_t)row * K + k0 + cols, (char*)Blds + c * 16);
    }
    __syncthreads();
    short8 af[4], bf[4];
#pragma unroll
    for (int m = 0; m < 4; m++) {
      const int row = wr * 64 + m * 16 + (lane & 15);
      const int cc = (lane >> 4) ^ (row & 3);
      af[m] = *(const short8*)((const char*)Alds + row * 64 + cc * 16);
    }
#pragma unroll
    for (int n = 0; n < 4; n++) {
      const int row = wc * 64 + n * 16 + (lane & 15);
      const int cc = (lane >> 4) ^ (row & 3);
      bf[n] = *(const short8*)((const char*)Blds + row * 64 + cc * 16);
    }
#pragma unroll
    for (int m = 0; m < 4; m++)
#pragma unroll
      for (int n = 0; n < 4; n++)
        acc[m][n] = __builtin_amdgcn_mfma_f32_16x16x32_bf16(af[m], bf[n], acc[m][n], 0, 0, 0);
    __syncthreads();
  }

#pragma unroll
  for (int m = 0; m < 4; m++)
#pragma unroll
    for (int n = 0; n < 4; n++)
#pragma unroll
      for (int r = 0; r < 4; r++) {
        const int row = m0 + wr * 64 + m * 16 + (lane >> 4) * 4 + r;
        const int col = n0 + wc * 64 + n * 16 + (lane & 15);
        if (OUTBF16)
          Cb[(size_t)row * N + col] = f2b(acc[m][n][r]);
        else
          Cf[(size_t)row * N + col] = acc[m][n][r];
      }
}

// ---------------- RoPE + split qkv -> Q[B,H,T,D], K[B,HK,T,D], V[B,HK,T,D] ----------------
__global__ __launch_bounds__(256)
void rope_kernel(const ushort* __restrict__ qkv, const float* __restrict__ cosp,
                 const float* __restrict__ sinp, ushort* __restrict__ Qo,
                 ushort* __restrict__ Ko, ushort* __restrict__ Vo) {
  const int row = blockIdx.x;            // b*2048 + t
  const int b = row >> 11, tt = row & 2047;
  const int i = threadIdx.x;
  const ushort* qr = qkv + (size_t)row * 6144;

  const int jb = (i & 7) * 8;            // d offset within lower half [0,64)
  float cs[8], sn[8];
  *(float4*)&cs[0] = *(const float4*)(cosp + tt * 128 + jb);
  *(float4*)&cs[4] = *(const float4*)(cosp + tt * 128 + jb + 4);
  *(float4*)&sn[0] = *(const float4*)(sinp + tt * 128 + jb);
  *(float4*)&sn[4] = *(const float4*)(sinp + tt * 128 + jb + 4);

  {  // Q: 32 heads x 8 d-pairs-of-8 -> 256 threads
    const int hh = i >> 3;
    short8 lo = *(const short8*)(qr + hh * 128 + jb);
    short8 hi = *(const short8*)(qr + hh * 128 + 64 + jb);
    short8 olo, ohi;
#pragma unroll
    for (int e = 0; e < 8; e++) {
      float fl = b2f((ushort)lo[e]), fh = b2f((ushort)hi[e]);
      olo[e] = (short)f2b(fl * cs[e] - fh * sn[e]);
      ohi[e] = (short)f2b(fh * cs[e] + fl * sn[e]);
    }
    ushort* dst = Qo + ((size_t)(b * 32 + hh) * 2048 + tt) * 128 + jb;
    *(short8*)dst = olo;
    *(short8*)(dst + 64) = ohi;
  }
  if (i < 64) {  // K: 8 kv-heads x 8 chunks
    const int hkk = i >> 3;
    short8 lo = *(const short8*)(qr + 4096 + hkk * 128 + jb);
    short8 hi = *(const short8*)(qr + 4096 + hkk * 128 + 64 + jb);
    short8 olo, ohi;
#pragma unroll
    for (int e = 0; e < 8; e++) {
      float fl = b2f((ushort)lo[e]), fh = b2f((ushort)hi[e]);
      olo[e] = (short)f2b(fl * cs[e] - fh * sn[e]);
      ohi[e] = (short)f2b(fh * cs[e] + fl * sn[e]);
    }
    ushort* dst = Ko + ((size_t)(b * 8 + hkk) * 2048 + tt) * 128 + jb;
    *(short8*)dst = olo;
    *(short8*)(dst + 64) = ohi;
  }
  {  // V copy: 1024 elems, 4 per thread
    const int e0 = i * 4;
    const int hkk = i >> 5;
    const int d = e0 & 127;
    ushort* dst = Vo + ((size_t)(b * 8 + hkk) * 2048 + tt) * 128 + d;
    *(short4v*)dst = *(const short4v*)(qr + 5120 + e0);
  }
}

// ---------------- causal GQA flash attention ----------------
// block = (b, h, 128 q rows); 4 waves x 32 rows; KV tile = 32.
#define ATT_SCALE 0.08838834764831845f

__device__ __forceinline__ int vt_off(int d, int kvc) {  // kvc = kv chunk (0..3)
  return d * 40 + ((kvc ^ ((d >> 3) & 3)) << 3);
}

__global__ __launch_bounds__(256, 2)
void attn_kernel(const ushort* __restrict__ Q, const ushort* __restrict__ Kg,
                 const ushort* __restrict__ Vg, ushort* __restrict__ O) {
  __shared__ __align__(16) ushort Klds[32 * 128];     // src-swizzled rows of 16B chunks
  __shared__ __align__(16) ushort Vt[128 * 40];       // V^T, stride 40, kv-chunk swizzle
  __shared__ __align__(16) ushort Plds[4][32 * 40];   // per-wave P, stride 40
  const int t = threadIdx.x, lane = t & 63, w = t >> 6;
  const int bx = blockIdx.x;
  const int qt = bx & 15;
  const int h = (bx >> 4) & 31;
  const int b = bx >> 9;
  const int hk = h >> 2;
  const int q0 = qt << 7;
  const int qw = q0 + w * 32;

  const ushort* Qp = Q + ((size_t)(b * 32 + h) * 2048) * 128;
  const ushort* Kp = Kg + ((size_t)(b * 8 + hk) * 2048) * 128;
  const ushort* Vp = Vg + ((size_t)(b * 8 + hk) * 2048) * 128;

  short8 qf[2][4];
#pragma unroll
  for (int m = 0; m < 2; m++)
#pragma unroll
    for (int kc = 0; kc < 4; kc++)
      qf[m][kc] = *(const short8*)(Qp + (size_t)(qw + m * 16 + (lane & 15)) * 128 +
                                   kc * 32 + (lane >> 4) * 8);

  floatx4 o[2][8];
#pragma unroll
  for (int m = 0; m < 2; m++)
#pragma unroll
    for (int dt = 0; dt < 8; dt++) o[m][dt] = (floatx4)(0.0f);
  float mrun[2][4], lrun[2][4];
#pragma unroll
  for (int m = 0; m < 2; m++)
#pragma unroll
    for (int r = 0; r < 4; r++) { mrun[m][r] = -3.0e38f; lrun[m][r] = 0.0f; }

  const int ntiles = (qt + 1) * 4;
  for (int it = 0; it < ntiles; ++it) {
    const int kv0 = it * 32;
    __syncthreads();
    // stage K (32x128), source-swizzled so reads are ~2-way conflict
#pragma unroll
    for (int j = 0; j < 2; j++) {
      const int c = j * 256 + t;
      const int krow = c >> 4, kcol = c & 15;
      const int colg = kcol ^ (krow & 7);
      gload_lds16(Kp + (size_t)(kv0 + krow) * 128 + colg * 8, (char*)Klds + c * 16);
    }
    // stage V transposed (reg-staged; 4-way write conflicts via kv-chunk swizzle)
#pragma unroll
    for (int j = 0; j < 2; j++) {
      const int c = j * 256 + t;
      const int vrow = c >> 4, vcol = c & 15;
      short8 v = *(const short8*)(Vp + (size_t)(kv0 + vrow) * 128 + vcol * 8);
#pragma unroll
      for (int e = 0; e < 8; e++)
        Vt[vt_off(vcol * 8 + e, vrow >> 3) + (vrow & 7)] = (ushort)v[e];
    }
    __syncthreads();

    if (kv0 <= qw) {
      // ---- QK^T ----
      floatx4 s[2][2];
#pragma unroll
      for (int m = 0; m < 2; m++)
#pragma unroll
        for (int n = 0; n < 2; n++) s[m][n] = (floatx4)(0.0f);
#pragma unroll
      for (int kc = 0; kc < 4; kc++) {
#pragma unroll
        for (int n = 0; n < 2; n++) {
          const int krow = n * 16 + (lane & 15);
          const int cc = (kc * 4 + (lane >> 4)) ^ (lane & 7);
          short8 kf = *(const short8*)((const char*)Klds + krow * 256 + cc * 16);
          s[0][n] = __builtin_amdgcn_mfma_f32_16x16x32_bf16(qf[0][kc], kf, s[0][n], 0, 0, 0);
          s[1][n] = __builtin_amdgcn_mfma_f32_16x16x32_bf16(qf[1][kc], kf, s[1][n], 0, 0, 0);
        }
      }
      // ---- scale + causal mask + row max ----
      float mx[2][4];
#pragma unroll
      for (int m = 0; m < 2; m++)
#pragma unroll
        for (int r = 0; r < 4; r++) {
          const int qg = qw + m * 16 + (lane >> 4) * 4 + r;
          float v0 = s[m][0][r] * ATT_SCALE;
          float v1 = s[m][1][r] * ATT_SCALE;
          if (kv0 + (lane & 15) > qg) v0 = -1e30f;
          if (kv0 + 16 + (lane & 15) > qg) v1 = -1e30f;
          s[m][0][r] = v0; s[m][1][r] = v1;
          mx[m][r] = fmaxf(v0, v1);
        }
#pragma unroll
      for (int off = 1; off < 16; off <<= 1)
#pragma unroll
        for (int m = 0; m < 2; m++)
#pragma unroll
          for (int r = 0; r < 4; r++)
            mx[m][r] = fmaxf(mx[m][r], __shfl_xor(mx[m][r], off, 64));
      float alpha[2][4], ls[2][4];
#pragma unroll
      for (int m = 0; m < 2; m++)
#pragma unroll
        for (int r = 0; r < 4; r++) {
          float mnew = fmaxf(mrun[m][r], mx[m][r]);
          alpha[m][r] = __expf(mrun[m][r] - mnew);
          mrun[m][r] = mnew;
          ls[m][r] = 0.0f;
        }
#pragma unroll
      for (int m = 0; m < 2; m++)
#pragma unroll
        for (int n = 0; n < 2; n++)
#pragma unroll
          for (int r = 0; r < 4; r++) {
            float p = __expf(s[m][n][r] - mrun[m][r]);
            s[m][n][r] = p;
            ls[m][r] += p;
          }
#pragma unroll
      for (int off = 1; off < 16; off <<= 1)
#pragma unroll
        for (int m = 0; m < 2; m++)
#pragma unroll
          for (int r = 0; r < 4; r++)
            ls[m][r] += __shfl_xor(ls[m][r], off, 64);
#pragma unroll
      for (int m = 0; m < 2; m++)
#pragma unroll
        for (int r = 0; r < 4; r++)
          lrun[m][r] = lrun[m][r] * alpha[m][r] + ls[m][r];
      // ---- P -> LDS (bf16), per-wave private (no barrier needed) ----
      ushort* Pw = Plds[w];
#pragma unroll
      for (int m = 0; m < 2; m++)
#pragma unroll
        for (int n = 0; n < 2; n++)
#pragma unroll
          for (int r = 0; r < 4; r++)
            Pw[(m * 16 + (lane >> 4) * 4 + r) * 40 + n * 16 + (lane & 15)] =
                f2b(s[m][n][r]);
      // ---- rescale O ----
#pragma unroll
      for (int m = 0; m < 2; m++)
#pragma unroll
        for (int dt = 0; dt < 8; dt++)
#pragma unroll
          for (int r = 0; r < 4; r++) o[m][dt][r] *= alpha[m][r];
      // ---- PV ----
      short8 pf0 = *(const short8*)&Pw[(lane & 15) * 40 + (lane >> 4) * 8];
      short8 pf1 = *(const short8*)&Pw[(16 + (lane & 15)) * 40 + (lane >> 4) * 8];
#pragma unroll
      for (int dt = 0; dt < 8; dt++) {
        short8 vf = *(const short8*)&Vt[vt_off(dt * 16 + (lane & 15), lane >> 4)];
        o[0][dt] = __builtin_amdgcn_mfma_f32_16x16x32_bf16(pf0, vf, o[0][dt], 0, 0, 0);
        o[1][dt] = __builtin_amdgcn_mfma_f32_16x16x32_bf16(pf1, vf, o[1][dt], 0, 0, 0);
      }
    }
  }
  // ---- epilogue: normalize, store bf16 [B*T, 4096] ----
#pragma unroll
  for (int m = 0; m < 2; m++)
#pragma unroll
    for (int r = 0; r < 4; r++) {
      const float inv = 1.0f / lrun[m][r];
      const int qg = qw + m * 16 + (lane >> 4) * 4 + r;
#pragma unroll
      for (int dt = 0; dt < 8; dt++)
        O[(size_t)(b * 2048 + qg) * 4096 + h * 128 + dt * 16 + (lane & 15)] =
            f2b(o[m][dt][r] * inv);
    }
}

// ---------------- launch ----------------
extern "C" void kernel_launch(void* const* d_in, const int* in_sizes, int n_in,
                              void* d_out, int out_size, void* d_ws, size_t ws_size,
                              hipStream_t stream) {
  const float* x = (const float*)d_in[0];
  const float* rc = (const float*)d_in[1];
  const float* rs = (const float*)d_in[2];
  const float* wqkv = (const float*)d_in[3];
  const float* wproj = (const float*)d_in[4];
  float* out = (float*)d_out;

  // workspace layout (ushort elements); total = 176 MB
  ushort* xb = (ushort*)d_ws;            // 16777216  (x bf16; reused late for W_proj bf16)
  ushort* wqkvb = xb + 16777216;         // 25165824
  ushort* qkvb = wqkvb + 25165824;       // 25165824  (qkv; reused for attn out)
  ushort* Qb = qkvb + 25165824;          // 16777216
  ushort* Kb = Qb + 16777216;            // 4194304
  ushort* Vb = Kb + 4194304;             // 4194304
  ushort* wprojb = xb;                   // alias: x dead after GEMM1
  ushort* aob = qkvb;                    // alias: qkv dead after rope

  cvt_kernel<<<2048, 256, 0, stream>>>(x, xb, 16777216L);
  cvt_kernel<<<2048, 256, 0, stream>>>(wqkv, wqkvb, 25165824L);
  gemm_bt<1><<<1536, 256, 0, stream>>>(xb, wqkvb, nullptr, qkvb, 4096, 6144, 4096);
  rope_kernel<<<4096, 256, 0, stream>>>(qkvb, rc, rs, Qb, Kb, Vb);
  attn_kernel<<<1024, 256, 0, stream>>>(Qb, Kb, Vb, aob);
  cvt_kernel<<<2048, 256, 0, stream>>>(wproj, wprojb, 16777216L);
  gemm_bt<0><<<1024, 256, 0, stream>>>(aob, wprojb, out, nullptr, 4096, 4096, 4096);
}

// Round 2
// 661.986 us; speedup vs baseline: 1.3449x; 1.3449x over previous
//
#include <hip/hip_runtime.h>
#include <hip/hip_bf16.h>

typedef __attribute__((ext_vector_type(8))) short short8;
typedef __attribute__((ext_vector_type(4))) short short4v;
typedef __attribute__((ext_vector_type(4))) float floatx4;

__device__ __forceinline__ float b2f(ushort u) {
  unsigned x = ((unsigned)u) << 16;
  return __builtin_bit_cast(float, x);
}
__device__ __forceinline__ ushort f2b(float f) {
  unsigned x = __builtin_bit_cast(unsigned, f);
  x += 0x7fffu + ((x >> 16) & 1u);
  return (ushort)(x >> 16);
}

__device__ __forceinline__ void gload_lds16(const void* g, void* l) {
  __builtin_amdgcn_global_load_lds(
      (const __attribute__((address_space(1))) unsigned int*)g,
      (__attribute__((address_space(3))) unsigned int*)l, 16, 0, 0);
}

// ---------------- f32 -> bf16 conversion ----------------
__global__ __launch_bounds__(256) void cvt_kernel(const float* __restrict__ in,
                                                  ushort* __restrict__ out, long n) {
  long i0 = ((long)blockIdx.x * 256 + threadIdx.x) * 4;
  long stride = (long)gridDim.x * 256 * 4;
  for (long i = i0; i < n; i += stride) {
    float4 v = *(const float4*)(in + i);
    ushort4 u;
    u.x = f2b(v.x); u.y = f2b(v.y); u.z = f2b(v.z); u.w = f2b(v.w);
    *(ushort4*)(out + i) = u;
  }
}

// ---------------- GEMM: C[M,N] = A[M,K] * B[N,K]^T (bf16 in, f32 acc) ----------------
template <int OUTBF16>
__global__ __launch_bounds__(256, 2)
void gemm_bt(const ushort* __restrict__ A, const ushort* __restrict__ B,
             float* __restrict__ Cf, ushort* __restrict__ Cb,
             int M, int N, int K) {
  __shared__ __align__(16) ushort Alds[128 * 32];
  __shared__ __align__(16) ushort Blds[128 * 32];
  const int t = threadIdx.x;
  const int lane = t & 63;
  const int w = t >> 6;
  const int ntn = N >> 7;
  const int nwg = gridDim.x;
  const int wg = blockIdx.x;
  const int swz = (wg & 7) * (nwg >> 3) + (wg >> 3);  // bijective: nwg % 8 == 0
  const int m0 = (swz / ntn) << 7;
  const int n0 = (swz % ntn) << 7;
  const int wr = w >> 1, wc = w & 1;

  floatx4 acc[4][4];
#pragma unroll
  for (int i = 0; i < 4; i++)
#pragma unroll
    for (int j = 0; j < 4; j++) acc[i][j] = (floatx4)(0.0f);

  const ushort* Ab = A + (size_t)m0 * K;
  const ushort* Bb = B + (size_t)n0 * K;

  for (int k0 = 0; k0 < K; k0 += 32) {
#pragma unroll
    for (int j = 0; j < 2; ++j) {
      const int c = j * 256 + t;
      const int row = c >> 2;
      const int cols = ((c & 3) ^ (row & 3)) * 8;
      gload_lds16(Ab + (size_t)row * K + k0 + cols, (char*)Alds + c * 16);
      gload_lds16(Bb + (size_t)row * K + k0 + cols, (char*)Blds + c * 16);
    }
    __syncthreads();
    short8 af[4], bf[4];
#pragma unroll
    for (int m = 0; m < 4; m++) {
      const int row = wr * 64 + m * 16 + (lane & 15);
      const int cc = (lane >> 4) ^ (row & 3);
      af[m] = *(const short8*)((const char*)Alds + row * 64 + cc * 16);
    }
#pragma unroll
    for (int n = 0; n < 4; n++) {
      const int row = wc * 64 + n * 16 + (lane & 15);
      const int cc = (lane >> 4) ^ (row & 3);
      bf[n] = *(const short8*)((const char*)Blds + row * 64 + cc * 16);
    }
#pragma unroll
    for (int m = 0; m < 4; m++)
#pragma unroll
      for (int n = 0; n < 4; n++)
        acc[m][n] = __builtin_amdgcn_mfma_f32_16x16x32_bf16(af[m], bf[n], acc[m][n], 0, 0, 0);
    __syncthreads();
  }

#pragma unroll
  for (int m = 0; m < 4; m++)
#pragma unroll
    for (int n = 0; n < 4; n++)
#pragma unroll
      for (int r = 0; r < 4; r++) {
        const int row = m0 + wr * 64 + m * 16 + (lane >> 4) * 4 + r;
        const int col = n0 + wc * 64 + n * 16 + (lane & 15);
        if (OUTBF16)
          Cb[(size_t)row * N + col] = f2b(acc[m][n][r]);
        else
          Cf[(size_t)row * N + col] = acc[m][n][r];
      }
}

// ---------------- RoPE + split qkv -> Q[B,H,T,D], K[B,HK,T,D] ----------------
__global__ __launch_bounds__(256)
void rope_kernel(const ushort* __restrict__ qkv, const float* __restrict__ cosp,
                 const float* __restrict__ sinp, ushort* __restrict__ Qo,
                 ushort* __restrict__ Ko) {
  const int row = blockIdx.x;            // b*2048 + t
  const int b = row >> 11, tt = row & 2047;
  const int i = threadIdx.x;
  const ushort* qr = qkv + (size_t)row * 6144;

  const int jb = (i & 7) * 8;            // d offset within lower half [0,64)
  float cs[8], sn[8];
  *(float4*)&cs[0] = *(const float4*)(cosp + tt * 128 + jb);
  *(float4*)&cs[4] = *(const float4*)(cosp + tt * 128 + jb + 4);
  *(float4*)&sn[0] = *(const float4*)(sinp + tt * 128 + jb);
  *(float4*)&sn[4] = *(const float4*)(sinp + tt * 128 + jb + 4);

  {  // Q: 32 heads x 8 chunks -> 256 threads
    const int hh = i >> 3;
    short8 lo = *(const short8*)(qr + hh * 128 + jb);
    short8 hi = *(const short8*)(qr + hh * 128 + 64 + jb);
    short8 olo, ohi;
#pragma unroll
    for (int e = 0; e < 8; e++) {
      float fl = b2f((ushort)lo[e]), fh = b2f((ushort)hi[e]);
      olo[e] = (short)f2b(fl * cs[e] - fh * sn[e]);
      ohi[e] = (short)f2b(fh * cs[e] + fl * sn[e]);
    }
    ushort* dst = Qo + ((size_t)(b * 32 + hh) * 2048 + tt) * 128 + jb;
    *(short8*)dst = olo;
    *(short8*)(dst + 64) = ohi;
  }
  if (i < 64) {  // K: 8 kv-heads x 8 chunks
    const int hkk = i >> 3;
    short8 lo = *(const short8*)(qr + 4096 + hkk * 128 + jb);
    short8 hi = *(const short8*)(qr + 4096 + hkk * 128 + 64 + jb);
    short8 olo, ohi;
#pragma unroll
    for (int e = 0; e < 8; e++) {
      float fl = b2f((ushort)lo[e]), fh = b2f((ushort)hi[e]);
      olo[e] = (short)f2b(fl * cs[e] - fh * sn[e]);
      ohi[e] = (short)f2b(fh * cs[e] + fl * sn[e]);
    }
    ushort* dst = Ko + ((size_t)(b * 8 + hkk) * 2048 + tt) * 128 + jb;
    *(short8*)dst = olo;
    *(short8*)(dst + 64) = ohi;
  }
}

// ---------------- V transpose: qkv V slice -> Vt[B,HK,D,T] ----------------
__global__ __launch_bounds__(256)
void vtrans_kernel(const ushort* __restrict__ qkv, ushort* __restrict__ Vt) {
  // grid: B * HK * (T/64) = 512
  const int bx = blockIdx.x;
  const int t0 = (bx & 31) * 64;
  const int hk = (bx >> 5) & 7;
  const int b = bx >> 8;
  const int i = threadIdx.x;
  const int tq = i & 15;           // t-quad within 64
  const int dn = i >> 4;           // d-octet (16 of them)
  const ushort* src = qkv + ((size_t)(b * 2048 + t0 + tq * 4)) * 6144 + 5120 + hk * 128 + dn * 8;
  short8 v0 = *(const short8*)(src);
  short8 v1 = *(const short8*)(src + 6144);
  short8 v2 = *(const short8*)(src + 12288);
  short8 v3 = *(const short8*)(src + 18432);
  ushort* dst = Vt + ((size_t)(b * 8 + hk) * 128 + dn * 8) * 2048 + t0 + tq * 4;
#pragma unroll
  for (int e = 0; e < 8; e++) {
    short4v pk;
    pk[0] = v0[e]; pk[1] = v1[e]; pk[2] = v2[e]; pk[3] = v3[e];
    *(short4v*)(dst + (size_t)e * 2048) = pk;
  }
}

// ---------------- causal GQA flash attention ----------------
// 512 blocks: (b, h, pair). Block does q-tiles qtA=pair, qtB=15-pair sequentially
// over a single double-buffered KV prefetch sequence (34 x KVBLK=64 tiles, uniform).
#define ATT_SCALE 0.08838834764831845f

__global__ __launch_bounds__(256, 2)
void attn_kernel(const ushort* __restrict__ Q, const ushort* __restrict__ Kg,
                 const ushort* __restrict__ Vtg, ushort* __restrict__ O) {
  __shared__ __align__(16) ushort Klds[2][64 * 128];   // [kv][d], chunk-XOR swizzled
  __shared__ __align__(16) ushort Vlds[2][128 * 64];   // [d][kv], chunk-XOR swizzled
  __shared__ __align__(16) ushort Plds[4][32 * 64];    // per-wave P, col^(r<<4) swizzle
  const int t = threadIdx.x, lane = t & 63, w = t >> 6;
  const int bx = blockIdx.x;
  const int pair = bx & 7;
  const int h = (bx >> 3) & 31;
  const int b = bx >> 8;
  const int hk = h >> 2;
  const int qtA = pair, qtB = 15 - pair;
  const int nA = (qtA + 1) * 2, nB = (qtB + 1) * 2;
  const int total = nA + nB;  // 34

  const ushort* Qp = Q + ((size_t)(b * 32 + h) * 2048) * 128;
  const ushort* Kp = Kg + ((size_t)(b * 8 + hk) * 2048) * 128;
  const ushort* Vp = Vtg + ((size_t)(b * 8 + hk) * 128) * 2048;

  const int L = lane & 15, g = lane >> 4;

  auto stage = [&](int s) {
    const int tt = (s < nA) ? s : s - nA;
    const int kv0 = tt * 64;
    ushort* Kd = Klds[s & 1];
    ushort* Vd = Vlds[s & 1];
#pragma unroll
    for (int j = 0; j < 4; j++) {
      const int c = j * 256 + t;
      const int krow = c >> 4, kcol = c & 15;
      gload_lds16(Kp + (size_t)(kv0 + krow) * 128 + ((kcol ^ (krow & 15)) << 3),
                  (char*)Kd + c * 16);
    }
#pragma unroll
    for (int j = 0; j < 4; j++) {
      const int c = j * 256 + t;
      const int d = c >> 3, tc = c & 7;
      gload_lds16(Vp + (size_t)d * 2048 + kv0 + ((tc ^ (d & 7)) << 3),
                  (char*)Vd + c * 16);
    }
  };

  short8 qf[2][4];
  floatx4 o[2][8];
  float mrun[2][4], lrun[2][4];

  auto init_pass = [&](int qw) {
#pragma unroll
    for (int m = 0; m < 2; m++) {
#pragma unroll
      for (int kc = 0; kc < 4; kc++)
        qf[m][kc] = *(const short8*)(Qp + (size_t)(qw + m * 16 + L) * 128 + kc * 32 + g * 8);
#pragma unroll
      for (int dt = 0; dt < 8; dt++) o[m][dt] = (floatx4)(0.0f);
#pragma unroll
      for (int r = 0; r < 4; r++) { mrun[m][r] = -3.0e38f; lrun[m][r] = 0.0f; }
    }
  };

  auto compute = [&](int tt, int bsel, int qw) {
    const int kv0 = tt * 64;
    if (kv0 > qw + 31) return;
    const ushort* Kd = Klds[bsel];
    const ushort* Vd = Vlds[bsel];
    ushort* Pw = Plds[w];
    // ---- QK^T: 32 q-rows x 64 kv ----
    floatx4 sfr[2][4];
#pragma unroll
    for (int m = 0; m < 2; m++)
#pragma unroll
      for (int n = 0; n < 4; n++) sfr[m][n] = (floatx4)(0.0f);
#pragma unroll
    for (int kc = 0; kc < 4; kc++) {
#pragma unroll
      for (int n = 0; n < 4; n++) {
        const int krow = n * 16 + L;
        const int ck = ((kc << 2) + g) ^ L;
        short8 kf = *(const short8*)((const char*)Kd + krow * 256 + ck * 16);
        sfr[0][n] = __builtin_amdgcn_mfma_f32_16x16x32_bf16(qf[0][kc], kf, sfr[0][n], 0, 0, 0);
        sfr[1][n] = __builtin_amdgcn_mfma_f32_16x16x32_bf16(qf[1][kc], kf, sfr[1][n], 0, 0, 0);
      }
    }
    // ---- scale + causal mask + row max ----
    float mx[2][4];
#pragma unroll
    for (int m = 0; m < 2; m++)
#pragma unroll
      for (int r = 0; r < 4; r++) {
        const int qg = qw + m * 16 + g * 4 + r;
        float mm = -3.0e38f;
#pragma unroll
        for (int n = 0; n < 4; n++) {
          float v = sfr[m][n][r] * ATT_SCALE;
          if (kv0 + n * 16 + L > qg) v = -1e30f;
          sfr[m][n][r] = v;
          mm = fmaxf(mm, v);
        }
        mx[m][r] = mm;
      }
#pragma unroll
    for (int off = 1; off < 16; off <<= 1)
#pragma unroll
      for (int m = 0; m < 2; m++)
#pragma unroll
        for (int r = 0; r < 4; r++)
          mx[m][r] = fmaxf(mx[m][r], __shfl_xor(mx[m][r], off, 64));
    float alpha[2][4], ls[2][4];
#pragma unroll
    for (int m = 0; m < 2; m++)
#pragma unroll
      for (int r = 0; r < 4; r++) {
        float mnew = fmaxf(mrun[m][r], mx[m][r]);
        alpha[m][r] = __expf(mrun[m][r] - mnew);
        mrun[m][r] = mnew;
        ls[m][r] = 0.0f;
      }
#pragma unroll
    for (int m = 0; m < 2; m++)
#pragma unroll
      for (int n = 0; n < 4; n++)
#pragma unroll
        for (int r = 0; r < 4; r++) {
          float p = __expf(sfr[m][n][r] - mrun[m][r]);
          sfr[m][n][r] = p;
          ls[m][r] += p;
        }
#pragma unroll
    for (int off = 1; off < 16; off <<= 1)
#pragma unroll
      for (int m = 0; m < 2; m++)
#pragma unroll
        for (int r = 0; r < 4; r++)
          ls[m][r] += __shfl_xor(ls[m][r], off, 64);
#pragma unroll
    for (int m = 0; m < 2; m++)
#pragma unroll
      for (int r = 0; r < 4; r++)
        lrun[m][r] = lrun[m][r] * alpha[m][r] + ls[m][r];
    // ---- P -> per-wave LDS (bf16), swizzled: elem (R,c) at R*64 + (c ^ ((R&3)<<4)) ----
#pragma unroll
    for (int m = 0; m < 2; m++)
#pragma unroll
      for (int n = 0; n < 4; n++)
#pragma unroll
        for (int r = 0; r < 4; r++) {
          const int R = m * 16 + g * 4 + r;
          const int col = n * 16 + L;
          Pw[R * 64 + (col ^ (r << 4))] = f2b(sfr[m][n][r]);
        }
    // ---- rescale O ----
#pragma unroll
    for (int m = 0; m < 2; m++)
#pragma unroll
      for (int dt = 0; dt < 8; dt++)
#pragma unroll
        for (int r = 0; r < 4; r++) o[m][dt][r] *= alpha[m][r];
    // ---- PV ----
#pragma unroll
    for (int kc = 0; kc < 2; kc++) {
      short8 pf[2];
#pragma unroll
      for (int m = 0; m < 2; m++) {
        const int R = m * 16 + L;
        const int C = kc * 32 + g * 8;
        pf[m] = *(const short8*)&Pw[R * 64 + (C ^ ((L & 3) << 4))];
      }
#pragma unroll
      for (int dt = 0; dt < 8; dt++) {
        const int d = dt * 16 + L;
        const int gp = ((kc << 2) + g) ^ (d & 7);
        short8 vf = *(const short8*)((const char*)Vd + d * 128 + gp * 16);
        o[0][dt] = __builtin_amdgcn_mfma_f32_16x16x32_bf16(pf[0], vf, o[0][dt], 0, 0, 0);
        o[1][dt] = __builtin_amdgcn_mfma_f32_16x16x32_bf16(pf[1], vf, o[1][dt], 0, 0, 0);
      }
    }
  };

  auto epilogue = [&](int qw) {
#pragma unroll
    for (int m = 0; m < 2; m++)
#pragma unroll
      for (int r = 0; r < 4; r++) {
        const float inv = 1.0f / lrun[m][r];
        const int qg = qw + m * 16 + g * 4 + r;
#pragma unroll
        for (int dt = 0; dt < 8; dt++)
          O[(size_t)(b * 2048 + qg) * 4096 + h * 128 + dt * 16 + L] =
              f2b(o[m][dt][r] * inv);
      }
  };

  int s = 0;
  stage(0);
  __syncthreads();

  int qw = qtA * 128 + w * 32;
  init_pass(qw);
  for (int i = 0; i < nA; ++i, ++s) {
    if (s + 1 < total) stage(s + 1);
    compute(i, s & 1, qw);
    __syncthreads();
  }
  epilogue(qw);

  qw = qtB * 128 + w * 32;
  init_pass(qw);
  for (int i = 0; i < nB; ++i, ++s) {
    if (s + 1 < total) stage(s + 1);
    compute(i, s & 1, qw);
    __syncthreads();
  }
  epilogue(qw);
}

// ---------------- launch ----------------
extern "C" void kernel_launch(void* const* d_in, const int* in_sizes, int n_in,
                              void* d_out, int out_size, void* d_ws, size_t ws_size,
                              hipStream_t stream) {
  const float* x = (const float*)d_in[0];
  const float* rc = (const float*)d_in[1];
  const float* rs = (const float*)d_in[2];
  const float* wqkv = (const float*)d_in[3];
  const float* wproj = (const float*)d_in[4];
  float* out = (float*)d_out;

  // workspace layout (ushort elements)
  ushort* xb = (ushort*)d_ws;            // 16777216  (x bf16; reused late for W_proj bf16)
  ushort* wqkvb = xb + 16777216;         // 25165824
  ushort* qkvb = wqkvb + 25165824;       // 25165824  (qkv; reused for attn out)
  ushort* Qb = qkvb + 25165824;          // 16777216
  ushort* Kb = Qb + 16777216;            // 4194304
  ushort* Vt = Kb + 4194304;             // 4194304   (V^T [B,HK,D,T])
  ushort* wprojb = xb;                   // alias: x dead after GEMM1
  ushort* aob = qkvb;                    // alias: qkv dead after vtrans

  cvt_kernel<<<2048, 256, 0, stream>>>(x, xb, 16777216L);
  cvt_kernel<<<2048, 256, 0, stream>>>(wqkv, wqkvb, 25165824L);
  gemm_bt<1><<<1536, 256, 0, stream>>>(xb, wqkvb, nullptr, qkvb, 4096, 6144, 4096);
  rope_kernel<<<4096, 256, 0, stream>>>(qkvb, rc, rs, Qb, Kb);
  vtrans_kernel<<<512, 256, 0, stream>>>(qkvb, Vt);
  attn_kernel<<<512, 256, 0, stream>>>(Qb, Kb, Vt, aob);
  cvt_kernel<<<2048, 256, 0, stream>>>(wproj, wprojb, 16777216L);
  gemm_bt<0><<<1024, 256, 0, stream>>>(aob, wprojb, out, nullptr, 4096, 4096, 4096);
}

// Round 3
// 614.677 us; speedup vs baseline: 1.4484x; 1.0770x over previous
//
#include <hip/hip_runtime.h>
#include <hip/hip_bf16.h>

typedef __attribute__((ext_vector_type(8))) short short8;
typedef __attribute__((ext_vector_type(4))) short short4v;
typedef __attribute__((ext_vector_type(4))) float floatx4;

__device__ __forceinline__ float b2f(ushort u) {
  unsigned x = ((unsigned)u) << 16;
  return __builtin_bit_cast(float, x);
}
__device__ __forceinline__ ushort f2b(float f) {
  unsigned x = __builtin_bit_cast(unsigned, f);
  x += 0x7fffu + ((x >> 16) & 1u);
  return (ushort)(x >> 16);
}

__device__ __forceinline__ void gload_lds16(const void* g, void* l) {
  __builtin_amdgcn_global_load_lds(
      (const __attribute__((address_space(1))) unsigned int*)g,
      (__attribute__((address_space(3))) unsigned int*)l, 16, 0, 0);
}

// ---------------- f32 -> bf16 conversion ----------------
__global__ __launch_bounds__(256) void cvt_kernel(const float* __restrict__ in,
                                                  ushort* __restrict__ out, long n) {
  long i0 = ((long)blockIdx.x * 256 + threadIdx.x) * 4;
  long stride = (long)gridDim.x * 256 * 4;
  for (long i = i0; i < n; i += stride) {
    float4 v = *(const float4*)(in + i);
    ushort4 u;
    u.x = f2b(v.x); u.y = f2b(v.y); u.z = f2b(v.z); u.w = f2b(v.w);
    *(ushort4*)(out + i) = u;
  }
}

// ---------------- 8-phase 256x256 GEMM: C[M,N] = A[M,K] * B[N,K]^T ----------------
// 512 threads (8 waves, 2Mx4N), BK=64 split in 2 k-subtiles, double-buffered 128KB LDS.
// Counted vmcnt(4) at 2-phase cadence (ledger-verified); raw barriers + lgkmcnt(0).
template <int OUTBF16>
__global__ __launch_bounds__(512, 2)
void gemm8p(const ushort* __restrict__ A, const ushort* __restrict__ B,
            float* __restrict__ Cf, ushort* __restrict__ Cb,
            int M, int N, int K) {
  __shared__ __align__(16) ushort sA[2][2][256 * 32];  // [buf][ksub][row*32+k]
  __shared__ __align__(16) ushort sB[2][2][256 * 32];
  const int t = threadIdx.x;
  const int lane = t & 63;
  const int L = lane & 15, g = lane >> 4;
  const int w = t >> 6;
  const int wr = w >> 2, wc = w & 3;   // 2 x 4 wave grid; per-wave C = 128x64
  const int ntn = N >> 8;
  const int nwg = gridDim.x;
  const int wg = blockIdx.x;
  const int swz = (wg & 7) * (nwg >> 3) + (wg >> 3);  // bijective: nwg % 8 == 0
  const int m0 = (swz / ntn) << 8;
  const int n0 = (swz % ntn) << 8;

  floatx4 acc[8][4];
#pragma unroll
  for (int i = 0; i < 8; i++)
#pragma unroll
    for (int j = 0; j < 4; j++) acc[i][j] = (floatx4)(0.0f);

  const ushort* Ab = A + (size_t)m0 * K;
  const ushort* Bb = B + (size_t)n0 * K;

  // stage one 16KB half-tile (256 rows x 32 k) linear-dest, source chunk-XOR swizzled
  auto stage_half = [&](const ushort* gbase, ushort* lds) {
#pragma unroll
    for (int j = 0; j < 2; j++) {
      const int c = j * 512 + t;               // 0..1023 16B chunks
      const int row = c >> 2, ch = c & 3;
      const int kc = ch ^ ((row >> 1) & 3);
      gload_lds16(gbase + (size_t)row * K + kc * 8, (char*)lds + c * 16);
    }
  };
  // fragment read with matching XOR (2 lanes/bank-quad => conflict-free)
  auto read_frag = [&](const ushort* half, int row) -> short8 {
    const int cc = g ^ ((row >> 1) & 3);
    return *(const short8*)((const char*)half + row * 64 + cc * 16);
  };

  short8 bfr[4];
  auto phase = [&](const ushort* Ah, const ushort* Bh, int mh,
                   const ushort* stG, ushort* stL, int vm) {
    if (mh == 0) {
#pragma unroll
      for (int nf = 0; nf < 4; nf++) bfr[nf] = read_frag(Bh, wc * 64 + nf * 16 + L);
    }
    short8 afr[4];
#pragma unroll
    for (int i = 0; i < 4; i++) afr[i] = read_frag(Ah, wr * 128 + mh * 64 + i * 16 + L);
    if (stG) stage_half(stG, stL);
    if (vm == 4) asm volatile("s_waitcnt vmcnt(4)" ::: "memory");
    else if (vm == 0) asm volatile("s_waitcnt vmcnt(0)" ::: "memory");
    __builtin_amdgcn_s_barrier();
    asm volatile("s_waitcnt lgkmcnt(0)" ::: "memory");
    __builtin_amdgcn_sched_barrier(0);
    __builtin_amdgcn_s_setprio(1);
#pragma unroll
    for (int i = 0; i < 4; i++)
#pragma unroll
      for (int nf = 0; nf < 4; nf++)
        acc[mh * 4 + i][nf] =
            __builtin_amdgcn_mfma_f32_16x16x32_bf16(afr[i], bfr[nf], acc[mh * 4 + i][nf], 0, 0, 0);
    __builtin_amdgcn_s_setprio(0);
    __builtin_amdgcn_s_barrier();
  };

  const int NT = K >> 6;
  // prologue: stage all 4 half-tiles of K-tile 0 into buf 0
  stage_half(Ab, &sA[0][0][0]);
  stage_half(Bb, &sB[0][0][0]);
  stage_half(Ab + 32, &sA[0][1][0]);
  stage_half(Bb + 32, &sB[0][1][0]);
  asm volatile("s_waitcnt vmcnt(4)" ::: "memory");
  __builtin_amdgcn_s_barrier();

  for (int T = 0; T < NT - 1; ++T) {
    const int bb = T & 1, nb = bb ^ 1;
    const ushort* At = Ab + (T + 1) * 64;
    const ushort* Bt = Bb + (T + 1) * 64;
    phase(&sA[bb][0][0], &sB[bb][0][0], 0, At,      &sA[nb][0][0], -1);
    phase(&sA[bb][0][0], &sB[bb][0][0], 1, Bt,      &sB[nb][0][0], 4);
    phase(&sA[bb][1][0], &sB[bb][1][0], 0, At + 32, &sA[nb][1][0], -1);
    phase(&sA[bb][1][0], &sB[bb][1][0], 1, Bt + 32, &sB[nb][1][0], 4);
  }
  {  // tail K-tile: no prefetch; one vmcnt(0) drain at the pair boundary
    const int bb = (NT - 1) & 1;
    phase(&sA[bb][0][0], &sB[bb][0][0], 0, nullptr, nullptr, -1);
    phase(&sA[bb][0][0], &sB[bb][0][0], 1, nullptr, nullptr, 0);
    phase(&sA[bb][1][0], &sB[bb][1][0], 0, nullptr, nullptr, -1);
    phase(&sA[bb][1][0], &sB[bb][1][0], 1, nullptr, nullptr, -1);
  }

#pragma unroll
  for (int mf = 0; mf < 8; mf++)
#pragma unroll
    for (int nf = 0; nf < 4; nf++)
#pragma unroll
      for (int r = 0; r < 4; r++) {
        const int row = m0 + wr * 128 + mf * 16 + g * 4 + r;
        const int col = n0 + wc * 64 + nf * 16 + L;
        if (OUTBF16)
          Cb[(size_t)row * N + col] = f2b(acc[mf][nf][r]);
        else
          Cf[(size_t)row * N + col] = acc[mf][nf][r];
      }
}

// ---------------- RoPE + split qkv -> Q[B,H,T,D], K[B,HK,T,D] ----------------
__global__ __launch_bounds__(256)
void rope_kernel(const ushort* __restrict__ qkv, const float* __restrict__ cosp,
                 const float* __restrict__ sinp, ushort* __restrict__ Qo,
                 ushort* __restrict__ Ko) {
  const int row = blockIdx.x;            // b*2048 + t
  const int b = row >> 11, tt = row & 2047;
  const int i = threadIdx.x;
  const ushort* qr = qkv + (size_t)row * 6144;

  const int jb = (i & 7) * 8;            // d offset within lower half [0,64)
  float cs[8], sn[8];
  *(float4*)&cs[0] = *(const float4*)(cosp + tt * 128 + jb);
  *(float4*)&cs[4] = *(const float4*)(cosp + tt * 128 + jb + 4);
  *(float4*)&sn[0] = *(const float4*)(sinp + tt * 128 + jb);
  *(float4*)&sn[4] = *(const float4*)(sinp + tt * 128 + jb + 4);

  {  // Q: 32 heads x 8 chunks -> 256 threads
    const int hh = i >> 3;
    short8 lo = *(const short8*)(qr + hh * 128 + jb);
    short8 hi = *(const short8*)(qr + hh * 128 + 64 + jb);
    short8 olo, ohi;
#pragma unroll
    for (int e = 0; e < 8; e++) {
      float fl = b2f((ushort)lo[e]), fh = b2f((ushort)hi[e]);
      olo[e] = (short)f2b(fl * cs[e] - fh * sn[e]);
      ohi[e] = (short)f2b(fh * cs[e] + fl * sn[e]);
    }
    ushort* dst = Qo + ((size_t)(b * 32 + hh) * 2048 + tt) * 128 + jb;
    *(short8*)dst = olo;
    *(short8*)(dst + 64) = ohi;
  }
  if (i < 64) {  // K: 8 kv-heads x 8 chunks
    const int hkk = i >> 3;
    short8 lo = *(const short8*)(qr + 4096 + hkk * 128 + jb);
    short8 hi = *(const short8*)(qr + 4096 + hkk * 128 + 64 + jb);
    short8 olo, ohi;
#pragma unroll
    for (int e = 0; e < 8; e++) {
      float fl = b2f((ushort)lo[e]), fh = b2f((ushort)hi[e]);
      olo[e] = (short)f2b(fl * cs[e] - fh * sn[e]);
      ohi[e] = (short)f2b(fh * cs[e] + fl * sn[e]);
    }
    ushort* dst = Ko + ((size_t)(b * 8 + hkk) * 2048 + tt) * 128 + jb;
    *(short8*)dst = olo;
    *(short8*)(dst + 64) = ohi;
  }
}

// ---------------- V transpose: qkv V slice -> Vt[B,HK,D,T] ----------------
__global__ __launch_bounds__(256)
void vtrans_kernel(const ushort* __restrict__ qkv, ushort* __restrict__ Vt) {
  // grid: B * HK * (T/64) = 512
  const int bx = blockIdx.x;
  const int t0 = (bx & 31) * 64;
  const int hk = (bx >> 5) & 7;
  const int b = bx >> 8;
  const int i = threadIdx.x;
  const int tq = i & 15;           // t-quad within 64
  const int dn = i >> 4;           // d-octet (16 of them)
  const ushort* src = qkv + ((size_t)(b * 2048 + t0 + tq * 4)) * 6144 + 5120 + hk * 128 + dn * 8;
  short8 v0 = *(const short8*)(src);
  short8 v1 = *(const short8*)(src + 6144);
  short8 v2 = *(const short8*)(src + 12288);
  short8 v3 = *(const short8*)(src + 18432);
  ushort* dst = Vt + ((size_t)(b * 8 + hk) * 128 + dn * 8) * 2048 + t0 + tq * 4;
#pragma unroll
  for (int e = 0; e < 8; e++) {
    short4v pk;
    pk[0] = v0[e]; pk[1] = v1[e]; pk[2] = v2[e]; pk[3] = v3[e];
    *(short4v*)(dst + (size_t)e * 2048) = pk;
  }
}

// ---------------- causal GQA flash attention ----------------
// 512 blocks: (b, h, pair). Block does q-tiles qtA=pair, qtB=15-pair sequentially
// over a single double-buffered KV prefetch sequence (34 x KVBLK=64 tiles, uniform).
#define ATT_SCALE 0.08838834764831845f

__global__ __launch_bounds__(256, 2)
void attn_kernel(const ushort* __restrict__ Q, const ushort* __restrict__ Kg,
                 const ushort* __restrict__ Vtg, ushort* __restrict__ O) {
  __shared__ __align__(16) ushort Klds[2][64 * 128];   // [kv][d], chunk-XOR swizzled
  __shared__ __align__(16) ushort Vlds[2][128 * 64];   // [d][kv], chunk-XOR swizzled
  __shared__ __align__(16) ushort Plds[4][32 * 64];    // per-wave P, col^(r<<4) swizzle
  const int t = threadIdx.x, lane = t & 63, w = t >> 6;
  const int bx = blockIdx.x;
  const int pair = bx & 7;
  const int h = (bx >> 3) & 31;
  const int b = bx >> 8;
  const int hk = h >> 2;
  const int qtA = pair, qtB = 15 - pair;
  const int nA = (qtA + 1) * 2, nB = (qtB + 1) * 2;
  const int total = nA + nB;  // 34

  const ushort* Qp = Q + ((size_t)(b * 32 + h) * 2048) * 128;
  const ushort* Kp = Kg + ((size_t)(b * 8 + hk) * 2048) * 128;
  const ushort* Vp = Vtg + ((size_t)(b * 8 + hk) * 128) * 2048;

  const int L = lane & 15, g = lane >> 4;

  auto stage = [&](int s) {
    const int tt = (s < nA) ? s : s - nA;
    const int kv0 = tt * 64;
    ushort* Kd = Klds[s & 1];
    ushort* Vd = Vlds[s & 1];
#pragma unroll
    for (int j = 0; j < 4; j++) {
      const int c = j * 256 + t;
      const int krow = c >> 4, kcol = c & 15;
      gload_lds16(Kp + (size_t)(kv0 + krow) * 128 + ((kcol ^ (krow & 15)) << 3),
                  (char*)Kd + c * 16);
    }
#pragma unroll
    for (int j = 0; j < 4; j++) {
      const int c = j * 256 + t;
      const int d = c >> 3, tc = c & 7;
      gload_lds16(Vp + (size_t)d * 2048 + kv0 + ((tc ^ (d & 7)) << 3),
                  (char*)Vd + c * 16);
    }
  };

  short8 qf[2][4];
  floatx4 o[2][8];
  float mrun[2][4], lrun[2][4];

  auto init_pass = [&](int qw) {
#pragma unroll
    for (int m = 0; m < 2; m++) {
#pragma unroll
      for (int kc = 0; kc < 4; kc++)
        qf[m][kc] = *(const short8*)(Qp + (size_t)(qw + m * 16 + L) * 128 + kc * 32 + g * 8);
#pragma unroll
      for (int dt = 0; dt < 8; dt++) o[m][dt] = (floatx4)(0.0f);
#pragma unroll
      for (int r = 0; r < 4; r++) { mrun[m][r] = -3.0e38f; lrun[m][r] = 0.0f; }
    }
  };

  auto compute = [&](int tt, int bsel, int qw) {
    const int kv0 = tt * 64;
    if (kv0 > qw + 31) return;
    const ushort* Kd = Klds[bsel];
    const ushort* Vd = Vlds[bsel];
    ushort* Pw = Plds[w];
    // ---- QK^T: 32 q-rows x 64 kv ----
    floatx4 sfr[2][4];
#pragma unroll
    for (int m = 0; m < 2; m++)
#pragma unroll
      for (int n = 0; n < 4; n++) sfr[m][n] = (floatx4)(0.0f);
#pragma unroll
    for (int kc = 0; kc < 4; kc++) {
#pragma unroll
      for (int n = 0; n < 4; n++) {
        const int krow = n * 16 + L;
        const int ck = ((kc << 2) + g) ^ L;
        short8 kf = *(const short8*)((const char*)Kd + krow * 256 + ck * 16);
        sfr[0][n] = __builtin_amdgcn_mfma_f32_16x16x32_bf16(qf[0][kc], kf, sfr[0][n], 0, 0, 0);
        sfr[1][n] = __builtin_amdgcn_mfma_f32_16x16x32_bf16(qf[1][kc], kf, sfr[1][n], 0, 0, 0);
      }
    }
    // ---- scale + causal mask + row max ----
    float mx[2][4];
#pragma unroll
    for (int m = 0; m < 2; m++)
#pragma unroll
      for (int r = 0; r < 4; r++) {
        const int qg = qw + m * 16 + g * 4 + r;
        float mm = -3.0e38f;
#pragma unroll
        for (int n = 0; n < 4; n++) {
          float v = sfr[m][n][r] * ATT_SCALE;
          if (kv0 + n * 16 + L > qg) v = -1e30f;
          sfr[m][n][r] = v;
          mm = fmaxf(mm, v);
        }
        mx[m][r] = mm;
      }
#pragma unroll
    for (int off = 1; off < 16; off <<= 1)
#pragma unroll
      for (int m = 0; m < 2; m++)
#pragma unroll
        for (int r = 0; r < 4; r++)
          mx[m][r] = fmaxf(mx[m][r], __shfl_xor(mx[m][r], off, 64));
    float alpha[2][4], ls[2][4];
#pragma unroll
    for (int m = 0; m < 2; m++)
#pragma unroll
      for (int r = 0; r < 4; r++) {
        float mnew = fmaxf(mrun[m][r], mx[m][r]);
        alpha[m][r] = __expf(mrun[m][r] - mnew);
        mrun[m][r] = mnew;
        ls[m][r] = 0.0f;
      }
#pragma unroll
    for (int m = 0; m < 2; m++)
#pragma unroll
      for (int n = 0; n < 4; n++)
#pragma unroll
        for (int r = 0; r < 4; r++) {
          float p = __expf(sfr[m][n][r] - mrun[m][r]);
          sfr[m][n][r] = p;
          ls[m][r] += p;
        }
#pragma unroll
    for (int off = 1; off < 16; off <<= 1)
#pragma unroll
      for (int m = 0; m < 2; m++)
#pragma unroll
        for (int r = 0; r < 4; r++)
          ls[m][r] += __shfl_xor(ls[m][r], off, 64);
#pragma unroll
    for (int m = 0; m < 2; m++)
#pragma unroll
      for (int r = 0; r < 4; r++)
        lrun[m][r] = lrun[m][r] * alpha[m][r] + ls[m][r];
    // ---- P -> per-wave LDS (bf16), swizzled: elem (R,c) at R*64 + (c ^ ((R&3)<<4)) ----
#pragma unroll
    for (int m = 0; m < 2; m++)
#pragma unroll
      for (int n = 0; n < 4; n++)
#pragma unroll
        for (int r = 0; r < 4; r++) {
          const int R = m * 16 + g * 4 + r;
          const int col = n * 16 + L;
          Pw[R * 64 + (col ^ (r << 4))] = f2b(sfr[m][n][r]);
        }
    // ---- rescale O ----
#pragma unroll
    for (int m = 0; m < 2; m++)
#pragma unroll
      for (int dt = 0; dt < 8; dt++)
#pragma unroll
        for (int r = 0; r < 4; r++) o[m][dt][r] *= alpha[m][r];
    // ---- PV ----
#pragma unroll
    for (int kc = 0; kc < 2; kc++) {
      short8 pf[2];
#pragma unroll
      for (int m = 0; m < 2; m++) {
        const int R = m * 16 + L;
        const int C = kc * 32 + g * 8;
        pf[m] = *(const short8*)&Pw[R * 64 + (C ^ ((L & 3) << 4))];
      }
#pragma unroll
      for (int dt = 0; dt < 8; dt++) {
        const int d = dt * 16 + L;
        const int gp = ((kc << 2) + g) ^ (d & 7);
        short8 vf = *(const short8*)((const char*)Vd + d * 128 + gp * 16);
        o[0][dt] = __builtin_amdgcn_mfma_f32_16x16x32_bf16(pf[0], vf, o[0][dt], 0, 0, 0);
        o[1][dt] = __builtin_amdgcn_mfma_f32_16x16x32_bf16(pf[1], vf, o[1][dt], 0, 0, 0);
      }
    }
  };

  auto epilogue = [&](int qw) {
#pragma unroll
    for (int m = 0; m < 2; m++)
#pragma unroll
      for (int r = 0; r < 4; r++) {
        const float inv = 1.0f / lrun[m][r];
        const int qg = qw + m * 16 + g * 4 + r;
#pragma unroll
        for (int dt = 0; dt < 8; dt++)
          O[(size_t)(b * 2048 + qg) * 4096 + h * 128 + dt * 16 + L] =
              f2b(o[m][dt][r] * inv);
      }
  };

  int s = 0;
  stage(0);
  __syncthreads();

  int qw = qtA * 128 + w * 32;
  init_pass(qw);
  for (int i = 0; i < nA; ++i, ++s) {
    if (s + 1 < total) stage(s + 1);
    compute(i, s & 1, qw);
    __syncthreads();
  }
  epilogue(qw);

  qw = qtB * 128 + w * 32;
  init_pass(qw);
  for (int i = 0; i < nB; ++i, ++s) {
    if (s + 1 < total) stage(s + 1);
    compute(i, s & 1, qw);
    __syncthreads();
  }
  epilogue(qw);
}

// ---------------- launch ----------------
extern "C" void kernel_launch(void* const* d_in, const int* in_sizes, int n_in,
                              void* d_out, int out_size, void* d_ws, size_t ws_size,
                              hipStream_t stream) {
  const float* x = (const float*)d_in[0];
  const float* rc = (const float*)d_in[1];
  const float* rs = (const float*)d_in[2];
  const float* wqkv = (const float*)d_in[3];
  const float* wproj = (const float*)d_in[4];
  float* out = (float*)d_out;

  // workspace layout (ushort elements)
  ushort* xb = (ushort*)d_ws;            // 16777216  (x bf16; reused late for W_proj bf16)
  ushort* wqkvb = xb + 16777216;         // 25165824
  ushort* qkvb = wqkvb + 25165824;       // 25165824  (qkv; reused for attn out)
  ushort* Qb = qkvb + 25165824;          // 16777216
  ushort* Kb = Qb + 16777216;            // 4194304
  ushort* Vt = Kb + 4194304;             // 4194304   (V^T [B,HK,D,T])
  ushort* wprojb = xb;                   // alias: x dead after GEMM1
  ushort* aob = qkvb;                    // alias: qkv dead after vtrans

  cvt_kernel<<<2048, 256, 0, stream>>>(x, xb, 16777216L);
  cvt_kernel<<<2048, 256, 0, stream>>>(wqkv, wqkvb, 25165824L);
  gemm8p<1><<<384, 512, 0, stream>>>(xb, wqkvb, nullptr, qkvb, 4096, 6144, 4096);
  rope_kernel<<<4096, 256, 0, stream>>>(qkvb, rc, rs, Qb, Kb);
  vtrans_kernel<<<512, 256, 0, stream>>>(qkvb, Vt);
  attn_kernel<<<512, 256, 0, stream>>>(Qb, Kb, Vt, aob);
  cvt_kernel<<<2048, 256, 0, stream>>>(wproj, wprojb, 16777216L);
  gemm8p<0><<<256, 512, 0, stream>>>(aob, wprojb, out, nullptr, 4096, 4096, 4096);
}

// Round 4
// 560.687 us; speedup vs baseline: 1.5879x; 1.0963x over previous
//
#include <hip/hip_runtime.h>
#include <hip/hip_bf16.h>

typedef __attribute__((ext_vector_type(8))) short short8;
typedef __attribute__((ext_vector_type(4))) short short4v;
typedef __attribute__((ext_vector_type(4))) float floatx4;

__device__ __forceinline__ float b2f(ushort u) {
  unsigned x = ((unsigned)u) << 16;
  return __builtin_bit_cast(float, x);
}
__device__ __forceinline__ ushort f2b(float f) {
  unsigned x = __builtin_bit_cast(unsigned, f);
  x += 0x7fffu + ((x >> 16) & 1u);
  return (ushort)(x >> 16);
}

__device__ __forceinline__ void gload_lds16(const void* g, void* l) {
  __builtin_amdgcn_global_load_lds(
      (const __attribute__((address_space(1))) unsigned int*)g,
      (__attribute__((address_space(3))) unsigned int*)l, 16, 0, 0);
}

// ---------------- f32 -> bf16 conversion ----------------
__global__ __launch_bounds__(256) void cvt_kernel(const float* __restrict__ in,
                                                  ushort* __restrict__ out, long n) {
  long i0 = ((long)blockIdx.x * 256 + threadIdx.x) * 4;
  long stride = (long)gridDim.x * 256 * 4;
  for (long i = i0; i < n; i += stride) {
    float4 v = *(const float4*)(in + i);
    ushort4 u;
    u.x = f2b(v.x); u.y = f2b(v.y); u.z = f2b(v.z); u.w = f2b(v.w);
    *(ushort4*)(out + i) = u;
  }
}

// ---------------- pipelined 256x256 GEMM: C[M,N] = A[M,K] * B[N,K]^T ----------------
// 8 waves (2Mx4N), BK=64, double-buffered 128KB LDS, ONE barrier + ONE vmcnt(0) per
// K-tile (__syncthreads == vmcnt(0)+lgkm(0)+s_barrier: exactly the depth-1 prefetch
// wait). Frag ds_reads are software-pipelined one phase ahead so the LDS pipe runs
// under the MFMA pipe (compiler emits counted lgkmcnt). Row-XOR chunk swizzle both
// sides (G4: byte ^= (row&7)<<4).
template <int OUTBF16>
__global__ __launch_bounds__(512, 2)
void gemm_pipe(const ushort* __restrict__ A, const ushort* __restrict__ B,
               float* __restrict__ Cf, ushort* __restrict__ Cb,
               int M, int N, int K) {
  __shared__ __align__(16) ushort sA[2][256 * 64];  // [buf][row*64 + k]
  __shared__ __align__(16) ushort sB[2][256 * 64];
  const int t = threadIdx.x;
  const int lane = t & 63;
  const int L = lane & 15, g = lane >> 4;
  const int w = t >> 6;
  const int wr = w >> 2, wc = w & 3;   // 2 x 4 wave grid; per-wave C = 128x64
  const int ntn = N >> 8;
  const int nwg = gridDim.x;
  const int wg = blockIdx.x;
  const int swz = (wg & 7) * (nwg >> 3) + (wg >> 3);  // bijective: nwg % 8 == 0
  const int m0 = (swz / ntn) << 8;
  const int n0 = (swz % ntn) << 8;

  floatx4 acc[8][4];
#pragma unroll
  for (int i = 0; i < 8; i++)
#pragma unroll
    for (int j = 0; j < 4; j++) acc[i][j] = (floatx4)(0.0f);

  const ushort* Ab = A + (size_t)m0 * K;
  const ushort* Bb = B + (size_t)n0 * K;

  // stage one full K-tile (256 rows x 64 k for A and B): 8 loads/thread
  auto stage_tile = [&](const ushort* Ag, const ushort* Bg, int buf) {
#pragma unroll
    for (int j = 0; j < 4; j++) {
      const int c = j * 512 + t;            // 0..2047 16B chunks
      const int row = c >> 3, ch = c & 7;
      const int kc = ch ^ (row & 7);        // source-side swizzle
      gload_lds16(Ag + (size_t)row * K + kc * 8, (char*)&sA[buf][0] + c * 16);
    }
#pragma unroll
    for (int j = 0; j < 4; j++) {
      const int c = j * 512 + t;
      const int row = c >> 3, ch = c & 7;
      const int kc = ch ^ (row & 7);
      gload_lds16(Bg + (size_t)row * K + kc * 8, (char*)&sB[buf][0] + c * 16);
    }
  };
  // frag reads with matching XOR (read-side swizzle)
  auto rdA = [&](int buf, int mh, int kc16, short8* dst) {
#pragma unroll
    for (int i = 0; i < 4; i++) {
      const int row = wr * 128 + mh * 64 + i * 16 + L;
      const int ch = (kc16 * 4 + g) ^ (row & 7);
      dst[i] = *(const short8*)((const char*)&sA[buf][0] + row * 128 + ch * 16);
    }
  };
  auto rdB = [&](int buf, int kc16, short8* dst) {
#pragma unroll
    for (int i = 0; i < 4; i++) {
      const int row = wc * 64 + i * 16 + L;
      const int ch = (kc16 * 4 + g) ^ (row & 7);
      dst[i] = *(const short8*)((const char*)&sB[buf][0] + row * 128 + ch * 16);
    }
  };

  short8 a0[4], a1[4], b0[4], b1[4];

  auto mfma16 = [&](short8* af, short8* bf, int accbase) {
    __builtin_amdgcn_s_setprio(1);
#pragma unroll
    for (int i = 0; i < 4; i++)
#pragma unroll
      for (int nf = 0; nf < 4; nf++)
        acc[accbase + i][nf] =
            __builtin_amdgcn_mfma_f32_16x16x32_bf16(af[i], bf[nf], acc[accbase + i][nf], 0, 0, 0);
    __builtin_amdgcn_s_setprio(0);
  };
  auto mfma8 = [&](short8* af, short8* bf, int accbase) {
    __builtin_amdgcn_s_setprio(1);
#pragma unroll
    for (int i = 0; i < 2; i++)
#pragma unroll
      for (int nf = 0; nf < 4; nf++)
        acc[accbase + i][nf] =
            __builtin_amdgcn_mfma_f32_16x16x32_bf16(af[i], bf[nf], acc[accbase + i][nf], 0, 0, 0);
    __builtin_amdgcn_s_setprio(0);
  };

  const int NT = K >> 6;
  // prologue: stage tile 0, then preload its first-phase frags
  stage_tile(Ab, Bb, 0);
  __syncthreads();
  rdA(0, 0, 0, a0);
  rdB(0, 0, b0);

  for (int T = 0; T < NT; ++T) {
    const int p = T & 1, q = p ^ 1;
    const bool more = (T + 1 < NT);
    if (more) stage_tile(Ab + (T + 1) * 64, Bb + (T + 1) * 64, q);
    rdA(p, 1, 0, a1);               // reads overlap mfma below (prev-phase regs)
    mfma16(a0, b0, 0);              // (kc0, mh0)
    rdA(p, 0, 1, a0);
    rdB(p, 1, b1);
    mfma16(a1, b0, 4);              // (kc0, mh1)
    rdA(p, 1, 1, a1);
    mfma16(a0, b1, 0);              // (kc1, mh0)
    mfma8(a1, b1, 4);               // (kc1, mh1) first half
    __syncthreads();                // vmcnt(0)+barrier: T+1 stages landed, p-reads done
    if (more) {                     // next tile's first-phase frags from q, overlapped
      rdA(q, 0, 0, a0);
      rdB(q, 0, b0);
    }
    mfma8(a1 + 2, b1, 6);           // (kc1, mh1) second half covers the q-reads
  }

#pragma unroll
  for (int mf = 0; mf < 8; mf++)
#pragma unroll
    for (int nf = 0; nf < 4; nf++)
#pragma unroll
      for (int r = 0; r < 4; r++) {
        const int row = m0 + wr * 128 + mf * 16 + g * 4 + r;
        const int col = n0 + wc * 64 + nf * 16 + L;
        if (OUTBF16)
          Cb[(size_t)row * N + col] = f2b(acc[mf][nf][r]);
        else
          Cf[(size_t)row * N + col] = acc[mf][nf][r];
      }
}

// ---------------- RoPE + split qkv -> Q[B,H,T,D], K[B,HK,T,D] ----------------
__global__ __launch_bounds__(256)
void rope_kernel(const ushort* __restrict__ qkv, const float* __restrict__ cosp,
                 const float* __restrict__ sinp, ushort* __restrict__ Qo,
                 ushort* __restrict__ Ko) {
  const int row = blockIdx.x;            // b*2048 + t
  const int b = row >> 11, tt = row & 2047;
  const int i = threadIdx.x;
  const ushort* qr = qkv + (size_t)row * 6144;

  const int jb = (i & 7) * 8;            // d offset within lower half [0,64)
  float cs[8], sn[8];
  *(float4*)&cs[0] = *(const float4*)(cosp + tt * 128 + jb);
  *(float4*)&cs[4] = *(const float4*)(cosp + tt * 128 + jb + 4);
  *(float4*)&sn[0] = *(const float4*)(sinp + tt * 128 + jb);
  *(float4*)&sn[4] = *(const float4*)(sinp + tt * 128 + jb + 4);

  {  // Q: 32 heads x 8 chunks -> 256 threads
    const int hh = i >> 3;
    short8 lo = *(const short8*)(qr + hh * 128 + jb);
    short8 hi = *(const short8*)(qr + hh * 128 + 64 + jb);
    short8 olo, ohi;
#pragma unroll
    for (int e = 0; e < 8; e++) {
      float fl = b2f((ushort)lo[e]), fh = b2f((ushort)hi[e]);
      olo[e] = (short)f2b(fl * cs[e] - fh * sn[e]);
      ohi[e] = (short)f2b(fh * cs[e] + fl * sn[e]);
    }
    ushort* dst = Qo + ((size_t)(b * 32 + hh) * 2048 + tt) * 128 + jb;
    *(short8*)dst = olo;
    *(short8*)(dst + 64) = ohi;
  }
  if (i < 64) {  // K: 8 kv-heads x 8 chunks
    const int hkk = i >> 3;
    short8 lo = *(const short8*)(qr + 4096 + hkk * 128 + jb);
    short8 hi = *(const short8*)(qr + 4096 + hkk * 128 + 64 + jb);
    short8 olo, ohi;
#pragma unroll
    for (int e = 0; e < 8; e++) {
      float fl = b2f((ushort)lo[e]), fh = b2f((ushort)hi[e]);
      olo[e] = (short)f2b(fl * cs[e] - fh * sn[e]);
      ohi[e] = (short)f2b(fh * cs[e] + fl * sn[e]);
    }
    ushort* dst = Ko + ((size_t)(b * 8 + hkk) * 2048 + tt) * 128 + jb;
    *(short8*)dst = olo;
    *(short8*)(dst + 64) = ohi;
  }
}

// ---------------- V transpose: qkv V slice -> Vt[B,HK,D,T] ----------------
__global__ __launch_bounds__(256)
void vtrans_kernel(const ushort* __restrict__ qkv, ushort* __restrict__ Vt) {
  // grid: B * HK * (T/64) = 512
  const int bx = blockIdx.x;
  const int t0 = (bx & 31) * 64;
  const int hk = (bx >> 5) & 7;
  const int b = bx >> 8;
  const int i = threadIdx.x;
  const int tq = i & 15;           // t-quad within 64
  const int dn = i >> 4;           // d-octet (16 of them)
  const ushort* src = qkv + ((size_t)(b * 2048 + t0 + tq * 4)) * 6144 + 5120 + hk * 128 + dn * 8;
  short8 v0 = *(const short8*)(src);
  short8 v1 = *(const short8*)(src + 6144);
  short8 v2 = *(const short8*)(src + 12288);
  short8 v3 = *(const short8*)(src + 18432);
  ushort* dst = Vt + ((size_t)(b * 8 + hk) * 128 + dn * 8) * 2048 + t0 + tq * 4;
#pragma unroll
  for (int e = 0; e < 8; e++) {
    short4v pk;
    pk[0] = v0[e]; pk[1] = v1[e]; pk[2] = v2[e]; pk[3] = v3[e];
    *(short4v*)(dst + (size_t)e * 2048) = pk;
  }
}

// ---------------- causal GQA flash attention ----------------
// 512 blocks: (b, h, pair). Block does q-tiles qtA=pair, qtB=15-pair sequentially
// over a single double-buffered KV prefetch sequence (34 x KVBLK=64 tiles, uniform).
#define ATT_SCALE 0.08838834764831845f

__global__ __launch_bounds__(256, 2)
void attn_kernel(const ushort* __restrict__ Q, const ushort* __restrict__ Kg,
                 const ushort* __restrict__ Vtg, ushort* __restrict__ O) {
  __shared__ __align__(16) ushort Klds[2][64 * 128];   // [kv][d], chunk-XOR swizzled
  __shared__ __align__(16) ushort Vlds[2][128 * 64];   // [d][kv], chunk-XOR swizzled
  __shared__ __align__(16) ushort Plds[4][32 * 64];    // per-wave P, col^(r<<4) swizzle
  const int t = threadIdx.x, lane = t & 63, w = t >> 6;
  const int bx = blockIdx.x;
  const int pair = bx & 7;
  const int h = (bx >> 3) & 31;
  const int b = bx >> 8;
  const int hk = h >> 2;
  const int qtA = pair, qtB = 15 - pair;
  const int nA = (qtA + 1) * 2, nB = (qtB + 1) * 2;
  const int total = nA + nB;  // 34

  const ushort* Qp = Q + ((size_t)(b * 32 + h) * 2048) * 128;
  const ushort* Kp = Kg + ((size_t)(b * 8 + hk) * 2048) * 128;
  const ushort* Vp = Vtg + ((size_t)(b * 8 + hk) * 128) * 2048;

  const int L = lane & 15, g = lane >> 4;

  auto stage = [&](int s) {
    const int tt = (s < nA) ? s : s - nA;
    const int kv0 = tt * 64;
    ushort* Kd = Klds[s & 1];
    ushort* Vd = Vlds[s & 1];
#pragma unroll
    for (int j = 0; j < 4; j++) {
      const int c = j * 256 + t;
      const int krow = c >> 4, kcol = c & 15;
      gload_lds16(Kp + (size_t)(kv0 + krow) * 128 + ((kcol ^ (krow & 15)) << 3),
                  (char*)Kd + c * 16);
    }
#pragma unroll
    for (int j = 0; j < 4; j++) {
      const int c = j * 256 + t;
      const int d = c >> 3, tc = c & 7;
      gload_lds16(Vp + (size_t)d * 2048 + kv0 + ((tc ^ (d & 7)) << 3),
                  (char*)Vd + c * 16);
    }
  };

  short8 qf[2][4];
  floatx4 o[2][8];
  float mrun[2][4], lrun[2][4];

  auto init_pass = [&](int qw) {
#pragma unroll
    for (int m = 0; m < 2; m++) {
#pragma unroll
      for (int kc = 0; kc < 4; kc++)
        qf[m][kc] = *(const short8*)(Qp + (size_t)(qw + m * 16 + L) * 128 + kc * 32 + g * 8);
#pragma unroll
      for (int dt = 0; dt < 8; dt++) o[m][dt] = (floatx4)(0.0f);
#pragma unroll
      for (int r = 0; r < 4; r++) { mrun[m][r] = -3.0e38f; lrun[m][r] = 0.0f; }
    }
  };

  auto compute = [&](int tt, int bsel, int qw) {
    const int kv0 = tt * 64;
    if (kv0 > qw + 31) return;
    const ushort* Kd = Klds[bsel];
    const ushort* Vd = Vlds[bsel];
    ushort* Pw = Plds[w];
    // ---- QK^T: 32 q-rows x 64 kv ----
    floatx4 sfr[2][4];
#pragma unroll
    for (int m = 0; m < 2; m++)
#pragma unroll
      for (int n = 0; n < 4; n++) sfr[m][n] = (floatx4)(0.0f);
#pragma unroll
    for (int kc = 0; kc < 4; kc++) {
#pragma unroll
      for (int n = 0; n < 4; n++) {
        const int krow = n * 16 + L;
        const int ck = ((kc << 2) + g) ^ L;
        short8 kf = *(const short8*)((const char*)Kd + krow * 256 + ck * 16);
        sfr[0][n] = __builtin_amdgcn_mfma_f32_16x16x32_bf16(qf[0][kc], kf, sfr[0][n], 0, 0, 0);
        sfr[1][n] = __builtin_amdgcn_mfma_f32_16x16x32_bf16(qf[1][kc], kf, sfr[1][n], 0, 0, 0);
      }
    }
    // ---- scale + causal mask + row max ----
    float mx[2][4];
#pragma unroll
    for (int m = 0; m < 2; m++)
#pragma unroll
      for (int r = 0; r < 4; r++) {
        const int qg = qw + m * 16 + g * 4 + r;
        float mm = -3.0e38f;
#pragma unroll
        for (int n = 0; n < 4; n++) {
          float v = sfr[m][n][r] * ATT_SCALE;
          if (kv0 + n * 16 + L > qg) v = -1e30f;
          sfr[m][n][r] = v;
          mm = fmaxf(mm, v);
        }
        mx[m][r] = mm;
      }
#pragma unroll
    for (int off = 1; off < 16; off <<= 1)
#pragma unroll
      for (int m = 0; m < 2; m++)
#pragma unroll
        for (int r = 0; r < 4; r++)
          mx[m][r] = fmaxf(mx[m][r], __shfl_xor(mx[m][r], off, 64));
    float alpha[2][4], ls[2][4];
#pragma unroll
    for (int m = 0; m < 2; m++)
#pragma unroll
      for (int r = 0; r < 4; r++) {
        float mnew = fmaxf(mrun[m][r], mx[m][r]);
        alpha[m][r] = __expf(mrun[m][r] - mnew);
        mrun[m][r] = mnew;
        ls[m][r] = 0.0f;
      }
#pragma unroll
    for (int m = 0; m < 2; m++)
#pragma unroll
      for (int n = 0; n < 4; n++)
#pragma unroll
        for (int r = 0; r < 4; r++) {
          float p = __expf(sfr[m][n][r] - mrun[m][r]);
          sfr[m][n][r] = p;
          ls[m][r] += p;
        }
#pragma unroll
    for (int off = 1; off < 16; off <<= 1)
#pragma unroll
      for (int m = 0; m < 2; m++)
#pragma unroll
        for (int r = 0; r < 4; r++)
          ls[m][r] += __shfl_xor(ls[m][r], off, 64);
#pragma unroll
    for (int m = 0; m < 2; m++)
#pragma unroll
      for (int r = 0; r < 4; r++)
        lrun[m][r] = lrun[m][r] * alpha[m][r] + ls[m][r];
    // ---- P -> per-wave LDS (bf16), swizzled: elem (R,c) at R*64 + (c ^ ((R&3)<<4)) ----
#pragma unroll
    for (int m = 0; m < 2; m++)
#pragma unroll
      for (int n = 0; n < 4; n++)
#pragma unroll
        for (int r = 0; r < 4; r++) {
          const int R = m * 16 + g * 4 + r;
          const int col = n * 16 + L;
          Pw[R * 64 + (col ^ (r << 4))] = f2b(sfr[m][n][r]);
        }
    // ---- rescale O ----
#pragma unroll
    for (int m = 0; m < 2; m++)
#pragma unroll
      for (int dt = 0; dt < 8; dt++)
#pragma unroll
        for (int r = 0; r < 4; r++) o[m][dt][r] *= alpha[m][r];
    // ---- PV ----
#pragma unroll
    for (int kc = 0; kc < 2; kc++) {
      short8 pf[2];
#pragma unroll
      for (int m = 0; m < 2; m++) {
        const int R = m * 16 + L;
        const int C = kc * 32 + g * 8;
        pf[m] = *(const short8*)&Pw[R * 64 + (C ^ ((L & 3) << 4))];
      }
#pragma unroll
      for (int dt = 0; dt < 8; dt++) {
        const int d = dt * 16 + L;
        const int gp = ((kc << 2) + g) ^ (d & 7);
        short8 vf = *(const short8*)((const char*)Vd + d * 128 + gp * 16);
        o[0][dt] = __builtin_amdgcn_mfma_f32_16x16x32_bf16(pf[0], vf, o[0][dt], 0, 0, 0);
        o[1][dt] = __builtin_amdgcn_mfma_f32_16x16x32_bf16(pf[1], vf, o[1][dt], 0, 0, 0);
      }
    }
  };

  auto epilogue = [&](int qw) {
#pragma unroll
    for (int m = 0; m < 2; m++)
#pragma unroll
      for (int r = 0; r < 4; r++) {
        const float inv = 1.0f / lrun[m][r];
        const int qg = qw + m * 16 + g * 4 + r;
#pragma unroll
        for (int dt = 0; dt < 8; dt++)
          O[(size_t)(b * 2048 + qg) * 4096 + h * 128 + dt * 16 + L] =
              f2b(o[m][dt][r] * inv);
      }
  };

  int s = 0;
  stage(0);
  __syncthreads();

  int qw = qtA * 128 + w * 32;
  init_pass(qw);
  for (int i = 0; i < nA; ++i, ++s) {
    if (s + 1 < total) stage(s + 1);
    compute(i, s & 1, qw);
    __syncthreads();
  }
  epilogue(qw);

  qw = qtB * 128 + w * 32;
  init_pass(qw);
  for (int i = 0; i < nB; ++i, ++s) {
    if (s + 1 < total) stage(s + 1);
    compute(i, s & 1, qw);
    __syncthreads();
  }
  epilogue(qw);
}

// ---------------- launch ----------------
extern "C" void kernel_launch(void* const* d_in, const int* in_sizes, int n_in,
                              void* d_out, int out_size, void* d_ws, size_t ws_size,
                              hipStream_t stream) {
  const float* x = (const float*)d_in[0];
  const float* rc = (const float*)d_in[1];
  const float* rs = (const float*)d_in[2];
  const float* wqkv = (const float*)d_in[3];
  const float* wproj = (const float*)d_in[4];
  float* out = (float*)d_out;

  // workspace layout (ushort elements)
  ushort* xb = (ushort*)d_ws;            // 16777216  (x bf16; reused late for W_proj bf16)
  ushort* wqkvb = xb + 16777216;         // 25165824
  ushort* qkvb = wqkvb + 25165824;       // 25165824  (qkv; reused for attn out)
  ushort* Qb = qkvb + 25165824;          // 16777216
  ushort* Kb = Qb + 16777216;            // 4194304
  ushort* Vt = Kb + 4194304;             // 4194304   (V^T [B,HK,D,T])
  ushort* wprojb = xb;                   // alias: x dead after GEMM1
  ushort* aob = qkvb;                    // alias: qkv dead after vtrans

  cvt_kernel<<<2048, 256, 0, stream>>>(x, xb, 16777216L);
  cvt_kernel<<<2048, 256, 0, stream>>>(wqkv, wqkvb, 25165824L);
  gemm_pipe<1><<<384, 512, 0, stream>>>(xb, wqkvb, nullptr, qkvb, 4096, 6144, 4096);
  rope_kernel<<<4096, 256, 0, stream>>>(qkvb, rc, rs, Qb, Kb);
  vtrans_kernel<<<512, 256, 0, stream>>>(qkvb, Vt);
  attn_kernel<<<512, 256, 0, stream>>>(Qb, Kb, Vt, aob);
  cvt_kernel<<<2048, 256, 0, stream>>>(wproj, wprojb, 16777216L);
  gemm_pipe<0><<<256, 512, 0, stream>>>(aob, wprojb, out, nullptr, 4096, 4096, 4096);
}

// Round 5
// 541.306 us; speedup vs baseline: 1.6447x; 1.0358x over previous
//
#include <hip/hip_runtime.h>
#include <hip/hip_bf16.h>

typedef __attribute__((ext_vector_type(8))) short short8;
typedef __attribute__((ext_vector_type(4))) short short4v;
typedef __attribute__((ext_vector_type(4))) float floatx4;

__device__ __forceinline__ float b2f(ushort u) {
  unsigned x = ((unsigned)u) << 16;
  return __builtin_bit_cast(float, x);
}
__device__ __forceinline__ ushort f2b(float f) {
  unsigned x = __builtin_bit_cast(unsigned, f);
  x += 0x7fffu + ((x >> 16) & 1u);
  return (ushort)(x >> 16);
}

__device__ __forceinline__ void gload_lds16(const void* g, void* l) {
  __builtin_amdgcn_global_load_lds(
      (const __attribute__((address_space(1))) unsigned int*)g,
      (__attribute__((address_space(3))) unsigned int*)l, 16, 0, 0);
}

// ---------------- f32 -> bf16 conversion ----------------
__global__ __launch_bounds__(256) void cvt_kernel(const float* __restrict__ in,
                                                  ushort* __restrict__ out, long n) {
  long i0 = ((long)blockIdx.x * 256 + threadIdx.x) * 4;
  long stride = (long)gridDim.x * 256 * 4;
  for (long i = i0; i < n; i += stride) {
    float4 v = *(const float4*)(in + i);
    ushort4 u;
    u.x = f2b(v.x); u.y = f2b(v.y); u.z = f2b(v.z); u.w = f2b(v.w);
    *(ushort4*)(out + i) = u;
  }
}

// ---------------- pipelined 256xBN GEMM: C[M,N] = A[M,K] * B[N,K]^T ----------------
// 8 waves (2Mx4N), BK=64, double-buffered LDS, ONE barrier + ONE vmcnt(0) per K-tile
// (__syncthreads == vmcnt(0)+lgkm(0)+s_barrier: the depth-1 prefetch wait). Frag
// ds_reads software-pipelined one phase ahead. Row-XOR chunk swizzle both sides.
// BN in {192, 256}: BN=192 gives 512 blocks on GEMM1 (perfect 2-round balance).
template <int BN, int OUTBF16>
__global__ __launch_bounds__(512, 2)
void gemm_pipe(const ushort* __restrict__ A, const ushort* __restrict__ B,
               float* __restrict__ Cf, ushort* __restrict__ Cb,
               int M, int N, int K) {
  constexpr int BNF = BN / 64;                      // B frags per wave (wave N = BN/4)
  __shared__ __align__(16) ushort sA[2][256 * 64];  // [buf][row*64 + k]
  __shared__ __align__(16) ushort sB[2][BN * 64];
  const int t = threadIdx.x;
  const int lane = t & 63;
  const int L = lane & 15, g = lane >> 4;
  const int w = t >> 6;
  const int wr = w >> 2, wc = w & 3;   // 2 x 4 wave grid; per-wave C = 128 x BN/4
  const int ntn = N / BN;
  const int nwg = gridDim.x;
  const int wg = blockIdx.x;
  const int swz = (wg & 7) * (nwg >> 3) + (wg >> 3);  // bijective: nwg % 8 == 0
  const int m0 = (swz / ntn) << 8;
  const int n0 = (swz % ntn) * BN;

  floatx4 acc[8][BNF];
#pragma unroll
  for (int i = 0; i < 8; i++)
#pragma unroll
    for (int j = 0; j < BNF; j++) acc[i][j] = (floatx4)(0.0f);

  const ushort* Ab = A + (size_t)m0 * K;
  const ushort* Bb = B + (size_t)n0 * K;

  // stage one full K-tile (256 rows A + BN rows B, 64 k) linear-dest, src swizzled
  auto stage_tile = [&](const ushort* Ag, const ushort* Bg, int buf) {
#pragma unroll
    for (int j = 0; j < 4; j++) {
      const int c = j * 512 + t;            // 0..2047 16B chunks
      const int row = c >> 3, ch = c & 7;
      const int kc = ch ^ (row & 7);        // source-side swizzle
      gload_lds16(Ag + (size_t)row * K + kc * 8, (char*)&sA[buf][0] + c * 16);
    }
#pragma unroll
    for (int j = 0; j < BNF; j++) {
      const int c = j * 512 + t;            // 0..BN*8-1
      const int row = c >> 3, ch = c & 7;
      const int kc = ch ^ (row & 7);
      gload_lds16(Bg + (size_t)row * K + kc * 8, (char*)&sB[buf][0] + c * 16);
    }
  };
  // frag reads with matching XOR (read-side swizzle)
  auto rdA = [&](int buf, int mh, int kc16, short8* dst) {
#pragma unroll
    for (int i = 0; i < 4; i++) {
      const int row = wr * 128 + mh * 64 + i * 16 + L;
      const int ch = (kc16 * 4 + g) ^ (row & 7);
      dst[i] = *(const short8*)((const char*)&sA[buf][0] + row * 128 + ch * 16);
    }
  };
  auto rdB = [&](int buf, int kc16, short8* dst) {
#pragma unroll
    for (int i = 0; i < BNF; i++) {
      const int row = wc * (BN / 4) + i * 16 + L;
      const int ch = (kc16 * 4 + g) ^ (row & 7);
      dst[i] = *(const short8*)((const char*)&sB[buf][0] + row * 128 + ch * 16);
    }
  };

  short8 a0[4], a1[4], b0[BNF], b1[BNF];

  auto mfmaN = [&](short8* af, short8* bf, int accbase, int cnt) {
    __builtin_amdgcn_s_setprio(1);
    for (int i = 0; i < cnt; i++)
#pragma unroll
      for (int nf = 0; nf < BNF; nf++)
        acc[accbase + i][nf] =
            __builtin_amdgcn_mfma_f32_16x16x32_bf16(af[i], bf[nf], acc[accbase + i][nf], 0, 0, 0);
    __builtin_amdgcn_s_setprio(0);
  };

  const int NT = K >> 6;
  // prologue: stage tile 0, then preload its first-phase frags
  stage_tile(Ab, Bb, 0);
  __syncthreads();
  rdA(0, 0, 0, a0);
  rdB(0, 0, b0);

  for (int T = 0; T < NT; ++T) {
    const int p = T & 1, q = p ^ 1;
    const bool more = (T + 1 < NT);
    if (more) stage_tile(Ab + (T + 1) * 64, Bb + (T + 1) * 64, q);
    rdA(p, 1, 0, a1);               // reads overlap mfma below (prev-phase regs)
    mfmaN(a0, b0, 0, 4);            // (kc0, mh0)
    rdA(p, 0, 1, a0);
    rdB(p, 1, b1);
    mfmaN(a1, b0, 4, 4);            // (kc0, mh1)
    rdA(p, 1, 1, a1);
    mfmaN(a0, b1, 0, 4);            // (kc1, mh0)
    mfmaN(a1, b1, 4, 2);            // (kc1, mh1) first half
    __syncthreads();                // vmcnt(0)+barrier: T+1 stages landed, p-reads done
    if (more) {                     // next tile's first-phase frags from q, overlapped
      rdA(q, 0, 0, a0);
      rdB(q, 0, b0);
    }
    mfmaN(a1 + 2, b1, 6, 2);        // (kc1, mh1) second half covers the q-reads
  }

#pragma unroll
  for (int mf = 0; mf < 8; mf++)
#pragma unroll
    for (int nf = 0; nf < BNF; nf++)
#pragma unroll
      for (int r = 0; r < 4; r++) {
        const int row = m0 + wr * 128 + mf * 16 + g * 4 + r;
        const int col = n0 + wc * (BN / 4) + nf * 16 + L;
        if (OUTBF16)
          Cb[(size_t)row * N + col] = f2b(acc[mf][nf][r]);
        else
          Cf[(size_t)row * N + col] = acc[mf][nf][r];
      }
}

// ---------------- RoPE + split qkv -> Q[B,H,T,D], K[B,HK,T,D] ----------------
__global__ __launch_bounds__(256)
void rope_kernel(const ushort* __restrict__ qkv, const float* __restrict__ cosp,
                 const float* __restrict__ sinp, ushort* __restrict__ Qo,
                 ushort* __restrict__ Ko) {
  const int row = blockIdx.x;            // b*2048 + t
  const int b = row >> 11, tt = row & 2047;
  const int i = threadIdx.x;
  const ushort* qr = qkv + (size_t)row * 6144;

  const int jb = (i & 7) * 8;            // d offset within lower half [0,64)
  float cs[8], sn[8];
  *(float4*)&cs[0] = *(const float4*)(cosp + tt * 128 + jb);
  *(float4*)&cs[4] = *(const float4*)(cosp + tt * 128 + jb + 4);
  *(float4*)&sn[0] = *(const float4*)(sinp + tt * 128 + jb);
  *(float4*)&sn[4] = *(const float4*)(sinp + tt * 128 + jb + 4);

  {  // Q: 32 heads x 8 chunks -> 256 threads
    const int hh = i >> 3;
    short8 lo = *(const short8*)(qr + hh * 128 + jb);
    short8 hi = *(const short8*)(qr + hh * 128 + 64 + jb);
    short8 olo, ohi;
#pragma unroll
    for (int e = 0; e < 8; e++) {
      float fl = b2f((ushort)lo[e]), fh = b2f((ushort)hi[e]);
      olo[e] = (short)f2b(fl * cs[e] - fh * sn[e]);
      ohi[e] = (short)f2b(fh * cs[e] + fl * sn[e]);
    }
    ushort* dst = Qo + ((size_t)(b * 32 + hh) * 2048 + tt) * 128 + jb;
    *(short8*)dst = olo;
    *(short8*)(dst + 64) = ohi;
  }
  if (i < 64) {  // K: 8 kv-heads x 8 chunks
    const int hkk = i >> 3;
    short8 lo = *(const short8*)(qr + 4096 + hkk * 128 + jb);
    short8 hi = *(const short8*)(qr + 4096 + hkk * 128 + 64 + jb);
    short8 olo, ohi;
#pragma unroll
    for (int e = 0; e < 8; e++) {
      float fl = b2f((ushort)lo[e]), fh = b2f((ushort)hi[e]);
      olo[e] = (short)f2b(fl * cs[e] - fh * sn[e]);
      ohi[e] = (short)f2b(fh * cs[e] + fl * sn[e]);
    }
    ushort* dst = Ko + ((size_t)(b * 8 + hkk) * 2048 + tt) * 128 + jb;
    *(short8*)dst = olo;
    *(short8*)(dst + 64) = ohi;
  }
}

// ---------------- V transpose: qkv V slice -> Vt[B,HK,D,T] ----------------
__global__ __launch_bounds__(256)
void vtrans_kernel(const ushort* __restrict__ qkv, ushort* __restrict__ Vt) {
  // grid: B * HK * (T/64) = 512
  const int bx = blockIdx.x;
  const int t0 = (bx & 31) * 64;
  const int hk = (bx >> 5) & 7;
  const int b = bx >> 8;
  const int i = threadIdx.x;
  const int tq = i & 15;           // t-quad within 64
  const int dn = i >> 4;           // d-octet (16 of them)
  const ushort* src = qkv + ((size_t)(b * 2048 + t0 + tq * 4)) * 6144 + 5120 + hk * 128 + dn * 8;
  short8 v0 = *(const short8*)(src);
  short8 v1 = *(const short8*)(src + 6144);
  short8 v2 = *(const short8*)(src + 12288);
  short8 v3 = *(const short8*)(src + 18432);
  ushort* dst = Vt + ((size_t)(b * 8 + hk) * 128 + dn * 8) * 2048 + t0 + tq * 4;
#pragma unroll
  for (int e = 0; e < 8; e++) {
    short4v pk;
    pk[0] = v0[e]; pk[1] = v1[e]; pk[2] = v2[e]; pk[3] = v3[e];
    *(short4v*)(dst + (size_t)e * 2048) = pk;
  }
}

// ---------------- causal GQA flash attention ----------------
// 512 blocks: (b, h, pair). Block does q-tiles qtA=pair, qtB=15-pair sequentially
// over a single double-buffered KV prefetch sequence (34 x KVBLK=64 tiles, uniform).
#define ATT_SCALE 0.08838834764831845f

__global__ __launch_bounds__(256, 2)
void attn_kernel(const ushort* __restrict__ Q, const ushort* __restrict__ Kg,
                 const ushort* __restrict__ Vtg, ushort* __restrict__ O) {
  __shared__ __align__(16) ushort Klds[2][64 * 128];   // [kv][d], chunk-XOR swizzled
  __shared__ __align__(16) ushort Vlds[2][128 * 64];   // [d][kv], chunk-XOR swizzled
  __shared__ __align__(16) ushort Plds[4][32 * 64];    // per-wave P, col^(r<<4) swizzle
  const int t = threadIdx.x, lane = t & 63, w = t >> 6;
  const int bx = blockIdx.x;
  const int pair = bx & 7;
  const int h = (bx >> 3) & 31;
  const int b = bx >> 8;
  const int hk = h >> 2;
  const int qtA = pair, qtB = 15 - pair;
  const int nA = (qtA + 1) * 2, nB = (qtB + 1) * 2;
  const int total = nA + nB;  // 34

  const ushort* Qp = Q + ((size_t)(b * 32 + h) * 2048) * 128;
  const ushort* Kp = Kg + ((size_t)(b * 8 + hk) * 2048) * 128;
  const ushort* Vp = Vtg + ((size_t)(b * 8 + hk) * 128) * 2048;

  const int L = lane & 15, g = lane >> 4;

  auto stage = [&](int s) {
    const int tt = (s < nA) ? s : s - nA;
    const int kv0 = tt * 64;
    ushort* Kd = Klds[s & 1];
    ushort* Vd = Vlds[s & 1];
#pragma unroll
    for (int j = 0; j < 4; j++) {
      const int c = j * 256 + t;
      const int krow = c >> 4, kcol = c & 15;
      gload_lds16(Kp + (size_t)(kv0 + krow) * 128 + ((kcol ^ (krow & 15)) << 3),
                  (char*)Kd + c * 16);
    }
#pragma unroll
    for (int j = 0; j < 4; j++) {
      const int c = j * 256 + t;
      const int d = c >> 3, tc = c & 7;
      gload_lds16(Vp + (size_t)d * 2048 + kv0 + ((tc ^ (d & 7)) << 3),
                  (char*)Vd + c * 16);
    }
  };

  short8 qf[2][4];
  floatx4 o[2][8];
  float mrun[2][4], lrun[2][4];

  auto init_pass = [&](int qw) {
#pragma unroll
    for (int m = 0; m < 2; m++) {
#pragma unroll
      for (int kc = 0; kc < 4; kc++)
        qf[m][kc] = *(const short8*)(Qp + (size_t)(qw + m * 16 + L) * 128 + kc * 32 + g * 8);
#pragma unroll
      for (int dt = 0; dt < 8; dt++) o[m][dt] = (floatx4)(0.0f);
#pragma unroll
      for (int r = 0; r < 4; r++) { mrun[m][r] = -3.0e38f; lrun[m][r] = 0.0f; }
    }
  };

  auto compute = [&](int tt, int bsel, int qw) {
    const int kv0 = tt * 64;
    if (kv0 > qw + 31) return;
    const ushort* Kd = Klds[bsel];
    const ushort* Vd = Vlds[bsel];
    ushort* Pw = Plds[w];
    // ---- QK^T: 32 q-rows x 64 kv ----
    floatx4 sfr[2][4];
#pragma unroll
    for (int m = 0; m < 2; m++)
#pragma unroll
      for (int n = 0; n < 4; n++) sfr[m][n] = (floatx4)(0.0f);
#pragma unroll
    for (int kc = 0; kc < 4; kc++) {
#pragma unroll
      for (int n = 0; n < 4; n++) {
        const int krow = n * 16 + L;
        const int ck = ((kc << 2) + g) ^ L;
        short8 kf = *(const short8*)((const char*)Kd + krow * 256 + ck * 16);
        sfr[0][n] = __builtin_amdgcn_mfma_f32_16x16x32_bf16(qf[0][kc], kf, sfr[0][n], 0, 0, 0);
        sfr[1][n] = __builtin_amdgcn_mfma_f32_16x16x32_bf16(qf[1][kc], kf, sfr[1][n], 0, 0, 0);
      }
    }
    // ---- scale + causal mask + row max ----
    float mx[2][4];
#pragma unroll
    for (int m = 0; m < 2; m++)
#pragma unroll
      for (int r = 0; r < 4; r++) {
        const int qg = qw + m * 16 + g * 4 + r;
        float mm = -3.0e38f;
#pragma unroll
        for (int n = 0; n < 4; n++) {
          float v = sfr[m][n][r] * ATT_SCALE;
          if (kv0 + n * 16 + L > qg) v = -1e30f;
          sfr[m][n][r] = v;
          mm = fmaxf(mm, v);
        }
        mx[m][r] = mm;
      }
#pragma unroll
    for (int off = 1; off < 16; off <<= 1)
#pragma unroll
      for (int m = 0; m < 2; m++)
#pragma unroll
        for (int r = 0; r < 4; r++)
          mx[m][r] = fmaxf(mx[m][r], __shfl_xor(mx[m][r], off, 64));
    float alpha[2][4], ls[2][4];
#pragma unroll
    for (int m = 0; m < 2; m++)
#pragma unroll
      for (int r = 0; r < 4; r++) {
        float mnew = fmaxf(mrun[m][r], mx[m][r]);
        alpha[m][r] = __expf(mrun[m][r] - mnew);
        mrun[m][r] = mnew;
        ls[m][r] = 0.0f;
      }
#pragma unroll
    for (int m = 0; m < 2; m++)
#pragma unroll
      for (int n = 0; n < 4; n++)
#pragma unroll
        for (int r = 0; r < 4; r++) {
          float p = __expf(sfr[m][n][r] - mrun[m][r]);
          sfr[m][n][r] = p;
          ls[m][r] += p;
        }
#pragma unroll
    for (int off = 1; off < 16; off <<= 1)
#pragma unroll
      for (int m = 0; m < 2; m++)
#pragma unroll
        for (int r = 0; r < 4; r++)
          ls[m][r] += __shfl_xor(ls[m][r], off, 64);
#pragma unroll
    for (int m = 0; m < 2; m++)
#pragma unroll
      for (int r = 0; r < 4; r++)
        lrun[m][r] = lrun[m][r] * alpha[m][r] + ls[m][r];
    // ---- P -> per-wave LDS (bf16), swizzled: elem (R,c) at R*64 + (c ^ ((R&3)<<4)) ----
#pragma unroll
    for (int m = 0; m < 2; m++)
#pragma unroll
      for (int n = 0; n < 4; n++)
#pragma unroll
        for (int r = 0; r < 4; r++) {
          const int R = m * 16 + g * 4 + r;
          const int col = n * 16 + L;
          Pw[R * 64 + (col ^ (r << 4))] = f2b(sfr[m][n][r]);
        }
    // ---- rescale O ----
#pragma unroll
    for (int m = 0; m < 2; m++)
#pragma unroll
      for (int dt = 0; dt < 8; dt++)
#pragma unroll
        for (int r = 0; r < 4; r++) o[m][dt][r] *= alpha[m][r];
    // ---- PV ----
#pragma unroll
    for (int kc = 0; kc < 2; kc++) {
      short8 pf[2];
#pragma unroll
      for (int m = 0; m < 2; m++) {
        const int R = m * 16 + L;
        const int C = kc * 32 + g * 8;
        pf[m] = *(const short8*)&Pw[R * 64 + (C ^ ((L & 3) << 4))];
      }
#pragma unroll
      for (int dt = 0; dt < 8; dt++) {
        const int d = dt * 16 + L;
        const int gp = ((kc << 2) + g) ^ (d & 7);
        short8 vf = *(const short8*)((const char*)Vd + d * 128 + gp * 16);
        o[0][dt] = __builtin_amdgcn_mfma_f32_16x16x32_bf16(pf[0], vf, o[0][dt], 0, 0, 0);
        o[1][dt] = __builtin_amdgcn_mfma_f32_16x16x32_bf16(pf[1], vf, o[1][dt], 0, 0, 0);
      }
    }
  };

  auto epilogue = [&](int qw) {
#pragma unroll
    for (int m = 0; m < 2; m++)
#pragma unroll
      for (int r = 0; r < 4; r++) {
        const float inv = 1.0f / lrun[m][r];
        const int qg = qw + m * 16 + g * 4 + r;
#pragma unroll
        for (int dt = 0; dt < 8; dt++)
          O[(size_t)(b * 2048 + qg) * 4096 + h * 128 + dt * 16 + L] =
              f2b(o[m][dt][r] * inv);
      }
  };

  int s = 0;
  stage(0);
  __syncthreads();

  int qw = qtA * 128 + w * 32;
  init_pass(qw);
  for (int i = 0; i < nA; ++i, ++s) {
    if (s + 1 < total) stage(s + 1);
    compute(i, s & 1, qw);
    __syncthreads();
  }
  epilogue(qw);

  qw = qtB * 128 + w * 32;
  init_pass(qw);
  for (int i = 0; i < nB; ++i, ++s) {
    if (s + 1 < total) stage(s + 1);
    compute(i, s & 1, qw);
    __syncthreads();
  }
  epilogue(qw);
}

// ---------------- launch ----------------
extern "C" void kernel_launch(void* const* d_in, const int* in_sizes, int n_in,
                              void* d_out, int out_size, void* d_ws, size_t ws_size,
                              hipStream_t stream) {
  const float* x = (const float*)d_in[0];
  const float* rc = (const float*)d_in[1];
  const float* rs = (const float*)d_in[2];
  const float* wqkv = (const float*)d_in[3];
  const float* wproj = (const float*)d_in[4];
  float* out = (float*)d_out;

  // workspace layout (ushort elements)
  ushort* xb = (ushort*)d_ws;            // 16777216  (x bf16; reused late for W_proj bf16)
  ushort* wqkvb = xb + 16777216;         // 25165824
  ushort* qkvb = wqkvb + 25165824;       // 25165824  (qkv; reused for attn out)
  ushort* Qb = qkvb + 25165824;          // 16777216
  ushort* Kb = Qb + 16777216;            // 4194304
  ushort* Vt = Kb + 4194304;             // 4194304   (V^T [B,HK,D,T])
  ushort* wprojb = xb;                   // alias: x dead after GEMM1
  ushort* aob = qkvb;                    // alias: qkv dead after vtrans

  cvt_kernel<<<2048, 256, 0, stream>>>(x, xb, 16777216L);
  cvt_kernel<<<2048, 256, 0, stream>>>(wqkv, wqkvb, 25165824L);
  gemm_pipe<192, 1><<<512, 512, 0, stream>>>(xb, wqkvb, nullptr, qkvb, 4096, 6144, 4096);
  rope_kernel<<<4096, 256, 0, stream>>>(qkvb, rc, rs, Qb, Kb);
  vtrans_kernel<<<512, 256, 0, stream>>>(qkvb, Vt);
  attn_kernel<<<512, 256, 0, stream>>>(Qb, Kb, Vt, aob);
  cvt_kernel<<<2048, 256, 0, stream>>>(wproj, wprojb, 16777216L);
  gemm_pipe<256, 0><<<256, 512, 0, stream>>>(aob, wprojb, out, nullptr, 4096, 4096, 4096);
}